// Round 1
// baseline (667.765 us; speedup 1.0000x reference)
//
#include <hip/hip_runtime.h>

// Problem constants (fixed by the reference):
#define NN    40000
#define EE    640000
#define INC   128
#define HID   256
#define OUTC  10
#define GG    64

// ---------------------------------------------------------------------------
// init: zero per-node int counters
__global__ void init_kernel(int* __restrict__ cnt, int* __restrict__ cursor, int n) {
    int i = blockIdx.x * blockDim.x + threadIdx.x;
    if (i < n) { cnt[i] = 0; cursor[i] = 0; }
}

// count in-degree (excluding self loop) via int atomics
__global__ void count_kernel(const int* __restrict__ dst, int* __restrict__ cnt, int e) {
    int i = blockIdx.x * blockDim.x + threadIdx.x;
    if (i < e) atomicAdd(&cnt[dst[i]], 1);
}

// exclusive scan of cnt -> offs (single block, 1024 threads, contiguous chunks)
__global__ __launch_bounds__(1024) void scan_kernel(const int* __restrict__ cnt,
                                                    int* __restrict__ offs, int n) {
    __shared__ int buf[1024];
    const int tid = threadIdx.x;
    const int per = (n + 1023) / 1024;
    const int start = tid * per;
    const int end   = min(start + per, n);
    int s = 0;
    for (int i = start; i < end; ++i) s += cnt[i];
    buf[tid] = s;
    __syncthreads();
    for (int off = 1; off < 1024; off <<= 1) {
        int t = (tid >= off) ? buf[tid - off] : 0;
        __syncthreads();
        buf[tid] += t;
        __syncthreads();
    }
    int run = buf[tid] - s;          // exclusive prefix for this thread's chunk
    for (int i = start; i < end; ++i) { offs[i] = run; run += cnt[i]; }
    if (tid == 1023) offs[n] = buf[1023];
}

// dis[n] = rsqrt(deg) with deg = edge in-degree + 1 (self loop)
__global__ void dis_kernel(const int* __restrict__ cnt, float* __restrict__ dis, int n) {
    int i = blockIdx.x * blockDim.x + threadIdx.x;
    if (i < n) dis[i] = rsqrtf((float)(cnt[i] + 1));
}

// CSR fill: col[offs[dst]+k] = src
__global__ void fill_kernel(const int* __restrict__ src, const int* __restrict__ dst,
                            const int* __restrict__ offs, int* __restrict__ cursor,
                            int* __restrict__ col, int e) {
    int i = blockIdx.x * blockDim.x + threadIdx.x;
    if (i < e) {
        int d = dst[i];
        int pos = offs[d] + atomicAdd(&cursor[d], 1);
        col[pos] = src[i];
    }
}

// ---------------------------------------------------------------------------
// GEMM: C[m,n] = dis[m] * sum_k A[m,k]*B[k,n]
// 128x128 block tile, BK=16, 256 threads, 8x8 microtile (split 4+4 quadrants).
#define GBM 128
#define GBN 128
#define GBK 16

__global__ __launch_bounds__(256) void gemm_scale_kernel(
    const float* __restrict__ A, const float* __restrict__ B,
    const float* __restrict__ dis, float* __restrict__ C,
    int M, int K, int N)
{
    __shared__ float As[GBK][GBM + 4];   // transposed: As[k][m]
    __shared__ float Bs[GBK][GBN + 4];
    const int tid = threadIdx.x;
    const int tx = tid & 15;             // 0..15 -> n groups
    const int ty = tid >> 4;             // 0..15 -> m groups
    const int m0 = blockIdx.x * GBM;
    const int n0 = blockIdx.y * GBN;

    float acc[8][8];
#pragma unroll
    for (int i = 0; i < 8; ++i)
#pragma unroll
        for (int j = 0; j < 8; ++j) acc[i][j] = 0.0f;

    for (int k0 = 0; k0 < K; k0 += GBK) {
        // load A tile (128 x 16), transposed into LDS
#pragma unroll
        for (int t = 0; t < 2; ++t) {
            int flat = tid + t * 256;          // 0..511 float4 slots
            int r = flat >> 2;                 // 0..127
            int c = (flat & 3) << 2;           // 0,4,8,12
            float4 v = make_float4(0.f, 0.f, 0.f, 0.f);
            int gr = m0 + r;
            if (gr < M) v = *(const float4*)(A + (size_t)gr * K + k0 + c);
            As[c + 0][r] = v.x; As[c + 1][r] = v.y;
            As[c + 2][r] = v.z; As[c + 3][r] = v.w;
        }
        // load B tile (16 x 128)
#pragma unroll
        for (int t = 0; t < 2; ++t) {
            int flat = tid + t * 256;
            int r = flat >> 5;                 // 0..15
            int c = (flat & 31) << 2;          // 0..124
            *(float4*)&Bs[r][c] = *(const float4*)(B + (size_t)(k0 + r) * N + n0 + c);
        }
        __syncthreads();
#pragma unroll
        for (int k = 0; k < GBK; ++k) {
            float4 a0 = *(const float4*)&As[k][ty * 4];
            float4 a1 = *(const float4*)&As[k][64 + ty * 4];
            float4 b0 = *(const float4*)&Bs[k][tx * 4];
            float4 b1 = *(const float4*)&Bs[k][64 + tx * 4];
            float am[8] = {a0.x, a0.y, a0.z, a0.w, a1.x, a1.y, a1.z, a1.w};
            float bn[8] = {b0.x, b0.y, b0.z, b0.w, b1.x, b1.y, b1.z, b1.w};
#pragma unroll
            for (int i = 0; i < 8; ++i)
#pragma unroll
                for (int j = 0; j < 8; ++j)
                    acc[i][j] = fmaf(am[i], bn[j], acc[i][j]);
        }
        __syncthreads();
    }

#pragma unroll
    for (int i = 0; i < 8; ++i) {
        int m = m0 + ((i < 4) ? (ty * 4 + i) : (64 + ty * 4 + (i - 4)));
        if (m < M) {
            float dm = dis[m];
            float4 o0 = make_float4(dm * acc[i][0], dm * acc[i][1],
                                    dm * acc[i][2], dm * acc[i][3]);
            float4 o1 = make_float4(dm * acc[i][4], dm * acc[i][5],
                                    dm * acc[i][6], dm * acc[i][7]);
            *(float4*)(C + (size_t)m * N + n0 + tx * 4)      = o0;
            *(float4*)(C + (size_t)m * N + n0 + 64 + tx * 4) = o1;
        }
    }
}

// ---------------------------------------------------------------------------
// Aggregation: out[n,:] = relu(dis[n]*(hs[n,:] + sum_{src in in(n)} hs[src,:]) + b)
// one 256-thread block per node, one feature per thread.
__global__ __launch_bounds__(256) void agg_kernel(
    const float* __restrict__ hs, const int* __restrict__ offs,
    const int* __restrict__ col, const float* __restrict__ dis,
    const float* __restrict__ bias, float* __restrict__ out)
{
    const int n = blockIdx.x;
    const int j = threadIdx.x;
    float acc = hs[(size_t)n * HID + j];
    const int lo = offs[n], hi = offs[n + 1];
    __shared__ int sidx[64];
    for (int base = lo; base < hi; base += 64) {
        int c = min(64, hi - base);
        __syncthreads();
        if (j < c) sidx[j] = col[base + j];
        __syncthreads();
        for (int i = 0; i < c; ++i)
            acc += hs[(size_t)sidx[i] * HID + j];
    }
    out[(size_t)n * HID + j] = fmaxf(fmaf(acc, dis[n], bias[j]), 0.0f);
}

// ---------------------------------------------------------------------------
// Pool (mean per graph; batch sorted) + final linear -> out[G, OUTC]
__global__ __launch_bounds__(256) void pool_linear_kernel(
    const float* __restrict__ h, const int* __restrict__ batch,
    const float* __restrict__ Wlin, const float* __restrict__ blin,
    float* __restrict__ out, int n_nodes)
{
    const int g = blockIdx.x;
    const int j = threadIdx.x;
    // lower_bound(batch, g)
    int lo = 0, hi = n_nodes;
    while (lo < hi) { int mid = (lo + hi) >> 1; if (batch[mid] < g) lo = mid + 1; else hi = mid; }
    const int start = lo;
    lo = start; hi = n_nodes;
    while (lo < hi) { int mid = (lo + hi) >> 1; if (batch[mid] < g + 1) lo = mid + 1; else hi = mid; }
    const int end = lo;

    float s = 0.0f;
    for (int r = start; r < end; ++r) s += h[(size_t)r * HID + j];
    float c = (float)(end - start);
    float pooled = s / fmaxf(c, 1.0f);

    __shared__ float pl[HID];
    pl[j] = pooled;
    __syncthreads();
    if (j < OUTC) {
        float o = blin[j];
        for (int k = 0; k < HID; ++k) o = fmaf(pl[k], Wlin[k * OUTC + j], o);
        out[g * OUTC + j] = o;
    }
}

// ---------------------------------------------------------------------------
extern "C" void kernel_launch(void* const* d_in, const int* in_sizes, int n_in,
                              void* d_out, int out_size, void* d_ws, size_t ws_size,
                              hipStream_t stream) {
    const float* x     = (const float*)d_in[0];
    const int*   ei    = (const int*)  d_in[1];   // [2, E]: row0 src, row1 dst
    const int*   batch = (const int*)  d_in[2];
    const float* W1    = (const float*)d_in[3];
    const float* b1    = (const float*)d_in[4];
    const float* W2    = (const float*)d_in[5];
    const float* b2    = (const float*)d_in[6];
    const float* Wlin  = (const float*)d_in[7];
    const float* blin  = (const float*)d_in[8];
    float* out = (float*)d_out;

    const int* src = ei;
    const int* dst = ei + EE;

    // workspace layout
    char* p = (char*)d_ws;
    float* bufA = (float*)p; p += (size_t)NN * HID * sizeof(float);   // hs1 / hs2
    float* bufB = (float*)p; p += (size_t)NN * HID * sizeof(float);   // h1f / h2f
    float* dis  = (float*)p; p += (size_t)NN * sizeof(float);
    int* cnt    = (int*)p;   p += (size_t)NN * sizeof(int);
    int* offs   = (int*)p;   p += (size_t)(NN + 4) * sizeof(int);
    int* cursor = (int*)p;   p += (size_t)NN * sizeof(int);
    int* col    = (int*)p;   p += (size_t)EE * sizeof(int);
    (void)ws_size; (void)n_in; (void)in_sizes; (void)out_size;

    const int TB = 256;
    const int nb_n = (NN + TB - 1) / TB;
    const int nb_e = (EE + TB - 1) / TB;

    // graph structure (rebuilt every call; ws is re-poisoned)
    init_kernel<<<nb_n, TB, 0, stream>>>(cnt, cursor, NN);
    count_kernel<<<nb_e, TB, 0, stream>>>(dst, cnt, EE);
    scan_kernel<<<1, 1024, 0, stream>>>(cnt, offs, NN);
    dis_kernel<<<nb_n, TB, 0, stream>>>(cnt, dis, NN);
    fill_kernel<<<nb_e, TB, 0, stream>>>(src, dst, offs, cursor, col, EE);

    dim3 ggrid((NN + GBM - 1) / GBM, HID / GBN);

    // layer 1: hs1 = dis .* (x @ W1); h1f = relu(dis.*(hs1 + gather) + b1)
    gemm_scale_kernel<<<ggrid, 256, 0, stream>>>(x, W1, dis, bufA, NN, INC, HID);
    agg_kernel<<<NN, 256, 0, stream>>>(bufA, offs, col, dis, b1, bufB);

    // layer 2: hs2 = dis .* (h1f @ W2); h2f = relu(dis.*(hs2 + gather) + b2)
    gemm_scale_kernel<<<ggrid, 256, 0, stream>>>(bufB, W2, dis, bufA, NN, HID, HID);
    agg_kernel<<<NN, 256, 0, stream>>>(bufA, offs, col, dis, b2, bufB);

    // pool + linear
    pool_linear_kernel<<<GG, 256, 0, stream>>>(bufB, batch, Wlin, blin, out, NN);
}

// Round 2
// 556.086 us; speedup vs baseline: 1.2008x; 1.2008x over previous
//
#include <hip/hip_runtime.h>

// Problem constants (fixed by the reference):
#define NN    40000
#define EE    640000
#define INC   128
#define HID   256
#define OUTC  10
#define GG    64

// ---------------------------------------------------------------------------
// init: zero per-node int counters + pooled accumulator
__global__ void init_kernel(int* __restrict__ cnt, int* __restrict__ cursor, int n,
                            float* __restrict__ pooled, int npool) {
    int i = blockIdx.x * blockDim.x + threadIdx.x;
    if (i < n) { cnt[i] = 0; cursor[i] = 0; }
    if (i < npool) pooled[i] = 0.0f;
}

// count in-degree (excluding self loop) via int atomics
__global__ void count_kernel(const int* __restrict__ dst, int* __restrict__ cnt, int e) {
    int i = blockIdx.x * blockDim.x + threadIdx.x;
    if (i < e) atomicAdd(&cnt[dst[i]], 1);
}

// exclusive scan of cnt -> offs (single block, 1024 threads, contiguous chunks)
__global__ __launch_bounds__(1024) void scan_kernel(const int* __restrict__ cnt,
                                                    int* __restrict__ offs, int n) {
    __shared__ int buf[1024];
    const int tid = threadIdx.x;
    const int per = (n + 1023) / 1024;
    const int start = tid * per;
    const int end   = min(start + per, n);
    int s = 0;
    for (int i = start; i < end; ++i) s += cnt[i];
    buf[tid] = s;
    __syncthreads();
    for (int off = 1; off < 1024; off <<= 1) {
        int t = (tid >= off) ? buf[tid - off] : 0;
        __syncthreads();
        buf[tid] += t;
        __syncthreads();
    }
    int run = buf[tid] - s;          // exclusive prefix for this thread's chunk
    for (int i = start; i < end; ++i) { offs[i] = run; run += cnt[i]; }
    if (tid == 1023) offs[n] = buf[1023];
}

// dis[n] = rsqrt(deg) with deg = edge in-degree + 1 (self loop)
__global__ void dis_kernel(const int* __restrict__ cnt, float* __restrict__ dis, int n) {
    int i = blockIdx.x * blockDim.x + threadIdx.x;
    if (i < n) dis[i] = rsqrtf((float)(cnt[i] + 1));
}

// CSR fill: col[offs[dst]+k] = src
__global__ void fill_kernel(const int* __restrict__ src, const int* __restrict__ dst,
                            const int* __restrict__ offs, int* __restrict__ cursor,
                            int* __restrict__ col, int e) {
    int i = blockIdx.x * blockDim.x + threadIdx.x;
    if (i < e) {
        int d = dst[i];
        int pos = offs[d] + atomicAdd(&cursor[d], 1);
        col[pos] = src[i];
    }
}

// ---------------------------------------------------------------------------
// GEMM: C[m,n] = dis[m] * sum_k A[m,k]*B[k,n]
// 128x128 block tile, BK=16, 256 threads, 8x8 microtile (split 4+4 quadrants).
#define GBM 128
#define GBN 128
#define GBK 16

__global__ __launch_bounds__(256) void gemm_scale_kernel(
    const float* __restrict__ A, const float* __restrict__ B,
    const float* __restrict__ dis, float* __restrict__ C,
    int M, int K, int N)
{
    __shared__ float As[GBK][GBM + 4];   // transposed: As[k][m]
    __shared__ float Bs[GBK][GBN + 4];
    const int tid = threadIdx.x;
    const int tx = tid & 15;             // 0..15 -> n groups
    const int ty = tid >> 4;             // 0..15 -> m groups
    const int m0 = blockIdx.x * GBM;
    const int n0 = blockIdx.y * GBN;

    float acc[8][8];
#pragma unroll
    for (int i = 0; i < 8; ++i)
#pragma unroll
        for (int j = 0; j < 8; ++j) acc[i][j] = 0.0f;

    for (int k0 = 0; k0 < K; k0 += GBK) {
        // load A tile (128 x 16), transposed into LDS
#pragma unroll
        for (int t = 0; t < 2; ++t) {
            int flat = tid + t * 256;          // 0..511 float4 slots
            int r = flat >> 2;                 // 0..127
            int c = (flat & 3) << 2;           // 0,4,8,12
            float4 v = make_float4(0.f, 0.f, 0.f, 0.f);
            int gr = m0 + r;
            if (gr < M) v = *(const float4*)(A + (size_t)gr * K + k0 + c);
            As[c + 0][r] = v.x; As[c + 1][r] = v.y;
            As[c + 2][r] = v.z; As[c + 3][r] = v.w;
        }
        // load B tile (16 x 128)
#pragma unroll
        for (int t = 0; t < 2; ++t) {
            int flat = tid + t * 256;
            int r = flat >> 5;                 // 0..15
            int c = (flat & 31) << 2;          // 0..124
            *(float4*)&Bs[r][c] = *(const float4*)(B + (size_t)(k0 + r) * N + n0 + c);
        }
        __syncthreads();
#pragma unroll
        for (int k = 0; k < GBK; ++k) {
            float4 a0 = *(const float4*)&As[k][ty * 4];
            float4 a1 = *(const float4*)&As[k][64 + ty * 4];
            float4 b0 = *(const float4*)&Bs[k][tx * 4];
            float4 b1 = *(const float4*)&Bs[k][64 + tx * 4];
            float am[8] = {a0.x, a0.y, a0.z, a0.w, a1.x, a1.y, a1.z, a1.w};
            float bn[8] = {b0.x, b0.y, b0.z, b0.w, b1.x, b1.y, b1.z, b1.w};
#pragma unroll
            for (int i = 0; i < 8; ++i)
#pragma unroll
                for (int j = 0; j < 8; ++j)
                    acc[i][j] = fmaf(am[i], bn[j], acc[i][j]);
        }
        __syncthreads();
    }

#pragma unroll
    for (int i = 0; i < 8; ++i) {
        int m = m0 + ((i < 4) ? (ty * 4 + i) : (64 + ty * 4 + (i - 4)));
        if (m < M) {
            float dm = dis[m];
            float4 o0 = make_float4(dm * acc[i][0], dm * acc[i][1],
                                    dm * acc[i][2], dm * acc[i][3]);
            float4 o1 = make_float4(dm * acc[i][4], dm * acc[i][5],
                                    dm * acc[i][6], dm * acc[i][7]);
            *(float4*)(C + (size_t)m * N + n0 + tx * 4)      = o0;
            *(float4*)(C + (size_t)m * N + n0 + 64 + tx * 4) = o1;
        }
    }
}

// ---------------------------------------------------------------------------
// Aggregation: out[n,:] = relu(dis[n]*(hs[n,:] + sum_{src in in(n)} hs[src,:]) + b)
// one 256-thread block per node, one feature per thread.
__global__ __launch_bounds__(256) void agg_kernel(
    const float* __restrict__ hs, const int* __restrict__ offs,
    const int* __restrict__ col, const float* __restrict__ dis,
    const float* __restrict__ bias, float* __restrict__ out)
{
    const int n = blockIdx.x;
    const int j = threadIdx.x;
    float acc = hs[(size_t)n * HID + j];
    const int lo = offs[n], hi = offs[n + 1];
    __shared__ int sidx[64];
    for (int base = lo; base < hi; base += 64) {
        int c = min(64, hi - base);
        __syncthreads();
        if (j < c) sidx[j] = col[base + j];
        __syncthreads();
        for (int i = 0; i < c; ++i)
            acc += hs[(size_t)sidx[i] * HID + j];
    }
    out[(size_t)n * HID + j] = fmaxf(fmaf(acc, dis[n], bias[j]), 0.0f);
}

// ---------------------------------------------------------------------------
// Pool phase 1: partial column sums per graph, chunked over nodes.
// Each block owns a contiguous node range; batch is sorted, so the range spans
// few graphs -> accumulate in register, flush on graph change via atomicAdd.
#define POOL_BLOCKS 320
__global__ __launch_bounds__(256) void pool_partial_kernel(
    const float* __restrict__ h, const int* __restrict__ batch,
    float* __restrict__ pooled, int n_nodes)
{
    const int j = threadIdx.x;
    const int per = (n_nodes + POOL_BLOCKS - 1) / POOL_BLOCKS;
    const int start = blockIdx.x * per;
    const int end   = min(start + per, n_nodes);
    if (start >= end) return;

    int curg = batch[start];
    float acc = 0.0f;
    for (int r = start; r < end; ++r) {
        int g = batch[r];
        if (g != curg) {
            atomicAdd(&pooled[(size_t)curg * HID + j], acc);
            acc = 0.0f;
            curg = g;
        }
        acc += h[(size_t)r * HID + j];
    }
    atomicAdd(&pooled[(size_t)curg * HID + j], acc);
}

// Pool phase 2: divide by counts (binary search on sorted batch) + final linear
__global__ __launch_bounds__(256) void pool_finalize_kernel(
    const float* __restrict__ pooled, const int* __restrict__ batch,
    const float* __restrict__ Wlin, const float* __restrict__ blin,
    float* __restrict__ out, int n_nodes)
{
    const int g = blockIdx.x;
    const int j = threadIdx.x;
    // lower_bound(batch, g) and lower_bound(batch, g+1)
    int lo = 0, hi = n_nodes;
    while (lo < hi) { int mid = (lo + hi) >> 1; if (batch[mid] < g) lo = mid + 1; else hi = mid; }
    const int start = lo;
    lo = start; hi = n_nodes;
    while (lo < hi) { int mid = (lo + hi) >> 1; if (batch[mid] < g + 1) lo = mid + 1; else hi = mid; }
    const int cnt = lo - start;

    float pv = pooled[(size_t)g * HID + j] / fmaxf((float)cnt, 1.0f);

    __shared__ float pl[HID];
    pl[j] = pv;
    __syncthreads();
    if (j < OUTC) {
        float o = blin[j];
        for (int k = 0; k < HID; ++k) o = fmaf(pl[k], Wlin[k * OUTC + j], o);
        out[g * OUTC + j] = o;
    }
}

// ---------------------------------------------------------------------------
extern "C" void kernel_launch(void* const* d_in, const int* in_sizes, int n_in,
                              void* d_out, int out_size, void* d_ws, size_t ws_size,
                              hipStream_t stream) {
    const float* x     = (const float*)d_in[0];
    const int*   ei    = (const int*)  d_in[1];   // [2, E]: row0 src, row1 dst
    const int*   batch = (const int*)  d_in[2];
    const float* W1    = (const float*)d_in[3];
    const float* b1    = (const float*)d_in[4];
    const float* W2    = (const float*)d_in[5];
    const float* b2    = (const float*)d_in[6];
    const float* Wlin  = (const float*)d_in[7];
    const float* blin  = (const float*)d_in[8];
    float* out = (float*)d_out;

    const int* src = ei;
    const int* dst = ei + EE;

    // workspace layout
    char* p = (char*)d_ws;
    float* bufA = (float*)p; p += (size_t)NN * HID * sizeof(float);   // hs1 / hs2
    float* bufB = (float*)p; p += (size_t)NN * HID * sizeof(float);   // h1f / h2f
    float* dis  = (float*)p; p += (size_t)NN * sizeof(float);
    float* pooled = (float*)p; p += (size_t)GG * HID * sizeof(float);
    int* cnt    = (int*)p;   p += (size_t)NN * sizeof(int);
    int* offs   = (int*)p;   p += (size_t)(NN + 4) * sizeof(int);
    int* cursor = (int*)p;   p += (size_t)NN * sizeof(int);
    int* col    = (int*)p;   p += (size_t)EE * sizeof(int);
    (void)ws_size; (void)n_in; (void)in_sizes; (void)out_size;

    const int TB = 256;
    const int nb_n = (NN + TB - 1) / TB;
    const int nb_e = (EE + TB - 1) / TB;

    // graph structure (rebuilt every call; ws is re-poisoned)
    init_kernel<<<nb_n, TB, 0, stream>>>(cnt, cursor, NN, pooled, GG * HID);
    count_kernel<<<nb_e, TB, 0, stream>>>(dst, cnt, EE);
    scan_kernel<<<1, 1024, 0, stream>>>(cnt, offs, NN);
    dis_kernel<<<nb_n, TB, 0, stream>>>(cnt, dis, NN);
    fill_kernel<<<nb_e, TB, 0, stream>>>(src, dst, offs, cursor, col, EE);

    dim3 ggrid((NN + GBM - 1) / GBM, HID / GBN);

    // layer 1: hs1 = dis .* (x @ W1); h1f = relu(dis.*(hs1 + gather) + b1)
    gemm_scale_kernel<<<ggrid, 256, 0, stream>>>(x, W1, dis, bufA, NN, INC, HID);
    agg_kernel<<<NN, 256, 0, stream>>>(bufA, offs, col, dis, b1, bufB);

    // layer 2: hs2 = dis .* (h1f @ W2); h2f = relu(dis.*(hs2 + gather) + b2)
    gemm_scale_kernel<<<ggrid, 256, 0, stream>>>(bufB, W2, dis, bufA, NN, HID, HID);
    agg_kernel<<<NN, 256, 0, stream>>>(bufA, offs, col, dis, b2, bufB);

    // pool (two-phase) + linear
    pool_partial_kernel<<<POOL_BLOCKS, 256, 0, stream>>>(bufB, batch, pooled, NN);
    pool_finalize_kernel<<<GG, 256, 0, stream>>>(pooled, batch, Wlin, blin, out, NN);
}

// Round 3
// 484.488 us; speedup vs baseline: 1.3783x; 1.1478x over previous
//
#include <hip/hip_runtime.h>

// Problem constants (fixed by the reference):
#define NN    40000
#define EE    640000
#define INC   128
#define HID   256
#define OUTC  10
#define GG    64

typedef unsigned short u16;

__device__ __forceinline__ float bf2f(u16 h) {
    return __uint_as_float(((unsigned)h) << 16);
}
__device__ __forceinline__ u16 f2bf(float f) {   // round-to-nearest-even
    unsigned u = __float_as_uint(f);
    unsigned r = u + 0x7FFFu + ((u >> 16) & 1u);
    return (u16)(r >> 16);
}

// ---------------------------------------------------------------------------
// init: zero per-node int counters + pooled accumulator
__global__ void init_kernel(int* __restrict__ cnt, int* __restrict__ cursor, int n,
                            float* __restrict__ pooled, int npool) {
    int i = blockIdx.x * blockDim.x + threadIdx.x;
    if (i < n) { cnt[i] = 0; cursor[i] = 0; }
    if (i < npool) pooled[i] = 0.0f;
}

// count in-degree (excluding self loop) via int atomics
__global__ void count_kernel(const int* __restrict__ dst, int* __restrict__ cnt, int e) {
    int i = blockIdx.x * blockDim.x + threadIdx.x;
    if (i < e) atomicAdd(&cnt[dst[i]], 1);
}

// exclusive scan of cnt -> offs (single block, 1024 threads, contiguous chunks)
__global__ __launch_bounds__(1024) void scan_kernel(const int* __restrict__ cnt,
                                                    int* __restrict__ offs, int n) {
    __shared__ int buf[1024];
    const int tid = threadIdx.x;
    const int per = (n + 1023) / 1024;
    const int start = tid * per;
    const int end   = min(start + per, n);
    int s = 0;
    for (int i = start; i < end; ++i) s += cnt[i];
    buf[tid] = s;
    __syncthreads();
    for (int off = 1; off < 1024; off <<= 1) {
        int t = (tid >= off) ? buf[tid - off] : 0;
        __syncthreads();
        buf[tid] += t;
        __syncthreads();
    }
    int run = buf[tid] - s;          // exclusive prefix for this thread's chunk
    for (int i = start; i < end; ++i) { offs[i] = run; run += cnt[i]; }
    if (tid == 1023) offs[n] = buf[1023];
}

// dis[n] = rsqrt(deg) with deg = edge in-degree + 1 (self loop)
__global__ void dis_kernel(const int* __restrict__ cnt, float* __restrict__ dis, int n) {
    int i = blockIdx.x * blockDim.x + threadIdx.x;
    if (i < n) dis[i] = rsqrtf((float)(cnt[i] + 1));
}

// CSR fill: col[offs[dst]+k] = src
__global__ void fill_kernel(const int* __restrict__ src, const int* __restrict__ dst,
                            const int* __restrict__ offs, int* __restrict__ cursor,
                            int* __restrict__ col, int e) {
    int i = blockIdx.x * blockDim.x + threadIdx.x;
    if (i < e) {
        int d = dst[i];
        int pos = offs[d] + atomicAdd(&cursor[d], 1);
        col[pos] = src[i];
    }
}

// xs = bf16(dis[row] * x) -- vectorized 4 elems/thread (INC divisible by 4)
__global__ void xs_kernel(const float* __restrict__ x, const float* __restrict__ dis,
                          u16* __restrict__ xs, int total4) {
    int i = blockIdx.x * blockDim.x + threadIdx.x;
    if (i < total4) {
        float4 v = ((const float4*)x)[i];
        int row = (i << 2) >> 7;            // /INC with INC=128
        float d = dis[row];
        ushort4 o;
        o.x = f2bf(v.x * d); o.y = f2bf(v.y * d);
        o.z = f2bf(v.z * d); o.w = f2bf(v.w * d);
        ((ushort4*)xs)[i] = o;
    }
}

// ---------------------------------------------------------------------------
// GEMM: acc = A[m,:] @ B[:,n]; out = relu(acc + bias[n]); if BF16OUT:
// out = bf16(dis[m]*out) else fp32 out.
// 128x128 block tile, BK=16, 256 threads, 8x8 microtile (split 4+4 quadrants).
#define GBM 128
#define GBN 128
#define GBK 16

template<bool BF16OUT>
__global__ __launch_bounds__(256) void gemm_kernel(
    const float* __restrict__ A, const float* __restrict__ B,
    const float* __restrict__ bias, const float* __restrict__ dis,
    void* __restrict__ Cout, int M, int K, int N)
{
    __shared__ float As[GBK][GBM + 4];   // transposed: As[k][m]
    __shared__ float Bs[GBK][GBN + 4];
    const int tid = threadIdx.x;
    const int tx = tid & 15;             // 0..15 -> n groups
    const int ty = tid >> 4;             // 0..15 -> m groups
    const int m0 = blockIdx.x * GBM;
    const int n0 = blockIdx.y * GBN;

    float acc[8][8];
#pragma unroll
    for (int i = 0; i < 8; ++i)
#pragma unroll
        for (int j = 0; j < 8; ++j) acc[i][j] = 0.0f;

    for (int k0 = 0; k0 < K; k0 += GBK) {
        // load A tile (128 x 16), transposed into LDS
#pragma unroll
        for (int t = 0; t < 2; ++t) {
            int flat = tid + t * 256;          // 0..511 float4 slots
            int r = flat >> 2;                 // 0..127
            int c = (flat & 3) << 2;           // 0,4,8,12
            float4 v = make_float4(0.f, 0.f, 0.f, 0.f);
            int gr = m0 + r;
            if (gr < M) v = *(const float4*)(A + (size_t)gr * K + k0 + c);
            As[c + 0][r] = v.x; As[c + 1][r] = v.y;
            As[c + 2][r] = v.z; As[c + 3][r] = v.w;
        }
        // load B tile (16 x 128)
#pragma unroll
        for (int t = 0; t < 2; ++t) {
            int flat = tid + t * 256;
            int r = flat >> 5;                 // 0..15
            int c = (flat & 31) << 2;          // 0..124
            *(float4*)&Bs[r][c] = *(const float4*)(B + (size_t)(k0 + r) * N + n0 + c);
        }
        __syncthreads();
#pragma unroll
        for (int k = 0; k < GBK; ++k) {
            float4 a0 = *(const float4*)&As[k][ty * 4];
            float4 a1 = *(const float4*)&As[k][64 + ty * 4];
            float4 b0 = *(const float4*)&Bs[k][tx * 4];
            float4 b1 = *(const float4*)&Bs[k][64 + tx * 4];
            float am[8] = {a0.x, a0.y, a0.z, a0.w, a1.x, a1.y, a1.z, a1.w};
            float bn[8] = {b0.x, b0.y, b0.z, b0.w, b1.x, b1.y, b1.z, b1.w};
#pragma unroll
            for (int i = 0; i < 8; ++i)
#pragma unroll
                for (int j = 0; j < 8; ++j)
                    acc[i][j] = fmaf(am[i], bn[j], acc[i][j]);
        }
        __syncthreads();
    }

    float bj0[4], bj1[4];
#pragma unroll
    for (int t = 0; t < 4; ++t) {
        bj0[t] = bias[n0 + tx * 4 + t];
        bj1[t] = bias[n0 + 64 + tx * 4 + t];
    }

#pragma unroll
    for (int i = 0; i < 8; ++i) {
        int m = m0 + ((i < 4) ? (ty * 4 + i) : (64 + ty * 4 + (i - 4)));
        if (m < M) {
            float v0[4], v1[4];
#pragma unroll
            for (int t = 0; t < 4; ++t) {
                v0[t] = fmaxf(acc[i][t]     + bj0[t], 0.0f);
                v1[t] = fmaxf(acc[i][4 + t] + bj1[t], 0.0f);
            }
            if (BF16OUT) {
                float dm = dis[m];
                u16* crow = (u16*)Cout + (size_t)m * N;
                ushort4 p0, p1;
                p0.x = f2bf(v0[0] * dm); p0.y = f2bf(v0[1] * dm);
                p0.z = f2bf(v0[2] * dm); p0.w = f2bf(v0[3] * dm);
                p1.x = f2bf(v1[0] * dm); p1.y = f2bf(v1[1] * dm);
                p1.z = f2bf(v1[2] * dm); p1.w = f2bf(v1[3] * dm);
                *(ushort4*)(crow + n0 + tx * 4)      = p0;
                *(ushort4*)(crow + n0 + 64 + tx * 4) = p1;
            } else {
                float* crow = (float*)Cout + (size_t)m * N;
                *(float4*)(crow + n0 + tx * 4)      = make_float4(v0[0], v0[1], v0[2], v0[3]);
                *(float4*)(crow + n0 + 64 + tx * 4) = make_float4(v1[0], v1[1], v1[2], v1[3]);
            }
        }
    }
}

// ---------------------------------------------------------------------------
// Aggregation (bf16 messages, fp32 accumulate):
// out[n,:] = dis[n] * (hs[n,:] + sum_{src in in(n)} hs[src,:])
// one F-thread block per node, one feature per thread.
template<int F>
__global__ __launch_bounds__(256) void agg_kernel(
    const u16* __restrict__ hs, const int* __restrict__ offs,
    const int* __restrict__ col, const float* __restrict__ dis,
    float* __restrict__ out)
{
    const int n = blockIdx.x;
    const int j = threadIdx.x;
    float acc = bf2f(hs[(size_t)n * F + j]);
    const int lo = offs[n], hi = offs[n + 1];
    __shared__ int sidx[64];
    for (int base = lo; base < hi; base += 64) {
        int c = min(64, hi - base);
        __syncthreads();
        if (j < c) sidx[j] = col[base + j];
        __syncthreads();
        for (int i = 0; i < c; ++i)
            acc += bf2f(hs[(size_t)sidx[i] * F + j]);
    }
    out[(size_t)n * F + j] = dis[n] * acc;
}

// ---------------------------------------------------------------------------
// Pool phase 1: partial column sums per graph, chunked over nodes.
#define POOL_BLOCKS 320
__global__ __launch_bounds__(256) void pool_partial_kernel(
    const float* __restrict__ h, const int* __restrict__ batch,
    float* __restrict__ pooled, int n_nodes)
{
    const int j = threadIdx.x;
    const int per = (n_nodes + POOL_BLOCKS - 1) / POOL_BLOCKS;
    const int start = blockIdx.x * per;
    const int end   = min(start + per, n_nodes);
    if (start >= end) return;

    int curg = batch[start];
    float acc = 0.0f;
    for (int r = start; r < end; ++r) {
        int g = batch[r];
        if (g != curg) {
            atomicAdd(&pooled[(size_t)curg * HID + j], acc);
            acc = 0.0f;
            curg = g;
        }
        acc += h[(size_t)r * HID + j];
    }
    atomicAdd(&pooled[(size_t)curg * HID + j], acc);
}

// Pool phase 2: divide by counts (binary search on sorted batch) + final linear
__global__ __launch_bounds__(256) void pool_finalize_kernel(
    const float* __restrict__ pooled, const int* __restrict__ batch,
    const float* __restrict__ Wlin, const float* __restrict__ blin,
    float* __restrict__ out, int n_nodes)
{
    const int g = blockIdx.x;
    const int j = threadIdx.x;
    int lo = 0, hi = n_nodes;
    while (lo < hi) { int mid = (lo + hi) >> 1; if (batch[mid] < g) lo = mid + 1; else hi = mid; }
    const int start = lo;
    lo = start; hi = n_nodes;
    while (lo < hi) { int mid = (lo + hi) >> 1; if (batch[mid] < g + 1) lo = mid + 1; else hi = mid; }
    const int cnt = lo - start;

    float pv = pooled[(size_t)g * HID + j] / fmaxf((float)cnt, 1.0f);

    __shared__ float pl[HID];
    pl[j] = pv;
    __syncthreads();
    if (j < OUTC) {
        float o = blin[j];
        for (int k = 0; k < HID; ++k) o = fmaf(pl[k], Wlin[k * OUTC + j], o);
        out[g * OUTC + j] = o;
    }
}

// ---------------------------------------------------------------------------
extern "C" void kernel_launch(void* const* d_in, const int* in_sizes, int n_in,
                              void* d_out, int out_size, void* d_ws, size_t ws_size,
                              hipStream_t stream) {
    const float* x     = (const float*)d_in[0];
    const int*   ei    = (const int*)  d_in[1];   // [2, E]: row0 src, row1 dst
    const int*   batch = (const int*)  d_in[2];
    const float* W1    = (const float*)d_in[3];
    const float* b1    = (const float*)d_in[4];
    const float* W2    = (const float*)d_in[5];
    const float* b2    = (const float*)d_in[6];
    const float* Wlin  = (const float*)d_in[7];
    const float* blin  = (const float*)d_in[8];
    float* out = (float*)d_out;

    const int* src = ei;
    const int* dst = ei + EE;

    // workspace layout (h2f aliases the [xs|xa|h1s] region, dead by then)
    char* p = (char*)d_ws;
    char* region0 = p;
    u16*   xs  = (u16*)p;   p += (size_t)NN * INC * sizeof(u16);    // 10.24 MB
    float* xa  = (float*)p; p += (size_t)NN * INC * sizeof(float);  // 20.48 MB
    u16*   h1s = (u16*)p;   p += (size_t)NN * HID * sizeof(u16);    // 20.48 MB
    float* a2  = (float*)p; p += (size_t)NN * HID * sizeof(float);  // 40.96 MB
    float* dis = (float*)p; p += (size_t)NN * sizeof(float);
    float* pooled = (float*)p; p += (size_t)GG * HID * sizeof(float);
    int* cnt    = (int*)p;  p += (size_t)NN * sizeof(int);
    int* offs   = (int*)p;  p += (size_t)(NN + 16) * sizeof(int);
    int* cursor = (int*)p;  p += (size_t)NN * sizeof(int);
    int* col    = (int*)p;  p += (size_t)EE * sizeof(int);
    float* h2f  = (float*)region0;   // 40.96 MB, aliases xs+xa+h1s (51.2 MB)
    (void)ws_size; (void)n_in; (void)in_sizes; (void)out_size;

    const int TB = 256;
    const int nb_n = (NN + TB - 1) / TB;
    const int nb_e = (EE + TB - 1) / TB;

    // graph structure (rebuilt every call; ws is re-poisoned)
    init_kernel<<<nb_n, TB, 0, stream>>>(cnt, cursor, NN, pooled, GG * HID);
    count_kernel<<<nb_e, TB, 0, stream>>>(dst, cnt, EE);
    scan_kernel<<<1, 1024, 0, stream>>>(cnt, offs, NN);
    dis_kernel<<<nb_n, TB, 0, stream>>>(cnt, dis, NN);
    fill_kernel<<<nb_e, TB, 0, stream>>>(src, dst, offs, cursor, col, EE);

    // xs = bf16(dis .* x)
    const int total4 = NN * INC / 4;
    xs_kernel<<<(total4 + TB - 1) / TB, TB, 0, stream>>>(x, dis, xs, total4);

    // layer 1 (aggregate-first): xa = dis .* (xs self + gather)   [fp32, 128-dim]
    agg_kernel<INC><<<NN, INC, 0, stream>>>(xs, offs, col, dis, xa);
    // h1s = bf16(dis .* relu(xa @ W1 + b1))
    dim3 ggrid((NN + GBM - 1) / GBM, HID / GBN);
    gemm_kernel<true><<<ggrid, 256, 0, stream>>>(xa, W1, b1, dis, (void*)h1s, NN, INC, HID);

    // layer 2 (aggregate-first): a2 = dis .* (h1s self + gather)  [fp32, 256-dim]
    agg_kernel<HID><<<NN, HID, 0, stream>>>(h1s, offs, col, dis, a2);
    // h2f = relu(a2 @ W2 + b2)
    gemm_kernel<false><<<ggrid, 256, 0, stream>>>(a2, W2, b2, dis, (void*)h2f, NN, HID, HID);

    // pool (two-phase) + linear
    pool_partial_kernel<<<POOL_BLOCKS, 256, 0, stream>>>(h2f, batch, pooled, NN);
    pool_finalize_kernel<<<GG, 256, 0, stream>>>(pooled, batch, Wlin, blin, out, NN);
}

// Round 4
// 449.500 us; speedup vs baseline: 1.4856x; 1.0778x over previous
//
#include <hip/hip_runtime.h>

// Problem constants (fixed by the reference):
#define NN    40000
#define EE    640000
#define INC   128
#define HID   256
#define OUTC  10
#define GG    64

typedef unsigned short u16;
typedef __attribute__((ext_vector_type(8))) short short8;   // 8 bf16 (4 VGPRs)
typedef __attribute__((ext_vector_type(4))) float f32x4;    // MFMA acc

__device__ __forceinline__ float bf2f(u16 h) {
    return __uint_as_float(((unsigned)h) << 16);
}
__device__ __forceinline__ u16 f2bf(float f) {   // round-to-nearest-even
    unsigned u = __float_as_uint(f);
    unsigned r = u + 0x7FFFu + ((u >> 16) & 1u);
    return (u16)(r >> 16);
}

// ---------------------------------------------------------------------------
// init: zero per-node int counters + pooled accumulator
__global__ void init_kernel(int* __restrict__ cnt, int* __restrict__ cursor, int n,
                            float* __restrict__ pooled, int npool) {
    int i = blockIdx.x * blockDim.x + threadIdx.x;
    if (i < n) { cnt[i] = 0; cursor[i] = 0; }
    if (i < npool) pooled[i] = 0.0f;
}

// count in-degree (excluding self loop) via int atomics
__global__ void count_kernel(const int* __restrict__ dst, int* __restrict__ cnt, int e) {
    int i = blockIdx.x * blockDim.x + threadIdx.x;
    if (i < e) atomicAdd(&cnt[dst[i]], 1);
}

// exclusive scan of cnt -> offs (single block, 1024 threads, contiguous chunks)
__global__ __launch_bounds__(1024) void scan_kernel(const int* __restrict__ cnt,
                                                    int* __restrict__ offs, int n) {
    __shared__ int buf[1024];
    const int tid = threadIdx.x;
    const int per = (n + 1023) / 1024;
    const int start = tid * per;
    const int end   = min(start + per, n);
    int s = 0;
    for (int i = start; i < end; ++i) s += cnt[i];
    buf[tid] = s;
    __syncthreads();
    for (int off = 1; off < 1024; off <<= 1) {
        int t = (tid >= off) ? buf[tid - off] : 0;
        __syncthreads();
        buf[tid] += t;
        __syncthreads();
    }
    int run = buf[tid] - s;          // exclusive prefix for this thread's chunk
    for (int i = start; i < end; ++i) { offs[i] = run; run += cnt[i]; }
    if (tid == 1023) offs[n] = buf[1023];
}

// dis[n] = rsqrt(deg) with deg = edge in-degree + 1 (self loop)
__global__ void dis_kernel(const int* __restrict__ cnt, float* __restrict__ dis, int n) {
    int i = blockIdx.x * blockDim.x + threadIdx.x;
    if (i < n) dis[i] = rsqrtf((float)(cnt[i] + 1));
}

// CSR fill: col[offs[dst]+k] = src
__global__ void fill_kernel(const int* __restrict__ src, const int* __restrict__ dst,
                            const int* __restrict__ offs, int* __restrict__ cursor,
                            int* __restrict__ col, int e) {
    int i = blockIdx.x * blockDim.x + threadIdx.x;
    if (i < e) {
        int d = dst[i];
        int pos = offs[d] + atomicAdd(&cursor[d], 1);
        col[pos] = src[i];
    }
}

// xs = bf16(dis[row] * x) -- vectorized 4 elems/thread (INC divisible by 4)
__global__ void xs_kernel(const float* __restrict__ x, const float* __restrict__ dis,
                          u16* __restrict__ xs, int total4) {
    int i = blockIdx.x * blockDim.x + threadIdx.x;
    if (i < total4) {
        float4 v = ((const float4*)x)[i];
        int row = (i << 2) >> 7;            // /INC with INC=128
        float d = dis[row];
        ushort4 o;
        o.x = f2bf(v.x * d); o.y = f2bf(v.y * d);
        o.z = f2bf(v.z * d); o.w = f2bf(v.w * d);
        ((ushort4*)xs)[i] = o;
    }
}

// W [K][N=256] fp32 -> transposed bf16 hi/lo planes Th/Tl [N=256][K]
__global__ void wsplit_kernel(const float* __restrict__ W, u16* __restrict__ Th,
                              u16* __restrict__ Tl, int K) {
    int i = blockIdx.x * blockDim.x + threadIdx.x;
    if (i < K * 256) {
        int k = i >> 8;          // /256
        int n = i & 255;
        float w = W[i];          // i == k*256 + n (row-major)
        u16 h = f2bf(w);
        float r = w - bf2f(h);
        Th[(size_t)n * K + k] = h;
        Tl[(size_t)n * K + k] = f2bf(r);
    }
}

// ---------------------------------------------------------------------------
// MFMA GEMM: C[M, 256] = A[M,K](bf16) @ (Wh+Wl)[K,256] (W stored transposed
// [256][K] bf16 hi/lo). Epilogue: v = relu(acc + bias[n]);
//   BF16OUT: store bf16(dis[m]*v), else store fp32 v.
// 128x128 tile, BK=32, 256 threads = 4 waves, each wave 4x4 16x16x32 tiles.
#define BM 128
#define BN 128
#define BK 32
#define LDP 40   // padded LDS row length (bf16 elems): 80 B -> 2-way aliasing only

template<bool BF16OUT>
__global__ __launch_bounds__(256) void mgemm_kernel(
    const u16* __restrict__ A,   // [M,K] bf16
    const u16* __restrict__ Bh,  // [256,K] bf16 (W^T hi)
    const u16* __restrict__ Bl,  // [256,K] bf16 (W^T lo)
    const float* __restrict__ bias,
    const float* __restrict__ dis,
    void* __restrict__ Cout, int M, int K)
{
    __shared__ u16 As [BM * LDP];
    __shared__ u16 Bhs[BN * LDP];
    __shared__ u16 Bls[BN * LDP];

    const int tid  = threadIdx.x;
    const int lane = tid & 63;
    const int wave = tid >> 6;
    const int ln   = lane & 15;        // col within 16x16 tile
    const int qd   = lane >> 4;        // quad: k-unit for A/B frags, row-quad for C
    const int wm   = (wave & 1) * 64;  // wave m-offset in tile
    const int wn   = (wave >> 1) * 64; // wave n-offset in tile
    const int m0   = blockIdx.x * BM;
    const int n0   = blockIdx.y * BN;

    f32x4 acc[4][4];
#pragma unroll
    for (int i = 0; i < 4; ++i)
#pragma unroll
        for (int j = 0; j < 4; ++j) acc[i][j] = (f32x4)(0.0f);

    for (int k0 = 0; k0 < K; k0 += BK) {
        // ---- stage A (128x32) and B hi/lo (128n x 32k) into LDS ----
        uint4 av[2], bhv[2], blv[2];
#pragma unroll
        for (int i = 0; i < 2; ++i) {
            int flat = tid + i * 256;          // 0..511 16B-units
            int r = flat >> 2;                 // 0..127 row
            int u = flat & 3;                  // k-unit (8 bf16)
            int grow = m0 + r;
            av[i] = make_uint4(0u, 0u, 0u, 0u);
            if (grow < M)
                av[i] = *(const uint4*)(A + (size_t)grow * K + k0 + u * 8);
            bhv[i] = *(const uint4*)(Bh + (size_t)(n0 + r) * K + k0 + u * 8);
            blv[i] = *(const uint4*)(Bl + (size_t)(n0 + r) * K + k0 + u * 8);
        }
        __syncthreads();   // previous chunk's frag reads complete
#pragma unroll
        for (int i = 0; i < 2; ++i) {
            int flat = tid + i * 256;
            int r = flat >> 2;
            int u = flat & 3;
            *(uint4*)(As  + r * LDP + u * 8) = av[i];
            *(uint4*)(Bhs + r * LDP + u * 8) = bhv[i];
            *(uint4*)(Bls + r * LDP + u * 8) = blv[i];
        }
        __syncthreads();

        // ---- fragments + MFMA ----
        short8 af[4], bfh[4], bfl[4];
#pragma unroll
        for (int t = 0; t < 4; ++t) {
            af[t]  = *(const short8*)(As  + (wm + t * 16 + ln) * LDP + qd * 8);
            bfh[t] = *(const short8*)(Bhs + (wn + t * 16 + ln) * LDP + qd * 8);
            bfl[t] = *(const short8*)(Bls + (wn + t * 16 + ln) * LDP + qd * 8);
        }
#pragma unroll
        for (int ti = 0; ti < 4; ++ti)
#pragma unroll
            for (int tj = 0; tj < 4; ++tj) {
                acc[ti][tj] = __builtin_amdgcn_mfma_f32_16x16x32_bf16(
                    af[ti], bfh[tj], acc[ti][tj], 0, 0, 0);
                acc[ti][tj] = __builtin_amdgcn_mfma_f32_16x16x32_bf16(
                    af[ti], bfl[tj], acc[ti][tj], 0, 0, 0);
            }
    }

    // ---- epilogue: C layout col=lane&15, row=qd*4+reg ----
    float bcol[4];
#pragma unroll
    for (int tj = 0; tj < 4; ++tj) bcol[tj] = bias[n0 + wn + tj * 16 + ln];

#pragma unroll
    for (int ti = 0; ti < 4; ++ti) {
#pragma unroll
        for (int r = 0; r < 4; ++r) {
            int row = m0 + wm + ti * 16 + qd * 4 + r;
            if (row < M) {
                if (BF16OUT) {
                    float dm = dis[row];
                    u16* crow = (u16*)Cout + (size_t)row * HID;
#pragma unroll
                    for (int tj = 0; tj < 4; ++tj) {
                        float v = fmaxf(acc[ti][tj][r] + bcol[tj], 0.0f);
                        crow[n0 + wn + tj * 16 + ln] = f2bf(v * dm);
                    }
                } else {
                    float* crow = (float*)Cout + (size_t)row * HID;
#pragma unroll
                    for (int tj = 0; tj < 4; ++tj) {
                        float v = fmaxf(acc[ti][tj][r] + bcol[tj], 0.0f);
                        crow[n0 + wn + tj * 16 + ln] = v;
                    }
                }
            }
        }
    }
}

// ---------------------------------------------------------------------------
// Aggregation (bf16 messages, fp32 accumulate, bf16 out):
// out[n,:] = bf16(dis[n] * (hs[n,:] + sum_{src in in(n)} hs[src,:]))
template<int F>
__global__ __launch_bounds__(256) void agg_kernel(
    const u16* __restrict__ hs, const int* __restrict__ offs,
    const int* __restrict__ col, const float* __restrict__ dis,
    u16* __restrict__ out)
{
    const int n = blockIdx.x;
    const int j = threadIdx.x;
    float acc = bf2f(hs[(size_t)n * F + j]);
    const int lo = offs[n], hi = offs[n + 1];
    __shared__ int sidx[64];
    for (int base = lo; base < hi; base += 64) {
        int c = min(64, hi - base);
        __syncthreads();
        if (j < c) sidx[j] = col[base + j];
        __syncthreads();
        for (int i = 0; i < c; ++i)
            acc += bf2f(hs[(size_t)sidx[i] * F + j]);
    }
    out[(size_t)n * F + j] = f2bf(dis[n] * acc);
}

// ---------------------------------------------------------------------------
// Pool phase 1: partial column sums per graph, chunked over nodes.
#define POOL_BLOCKS 320
__global__ __launch_bounds__(256) void pool_partial_kernel(
    const float* __restrict__ h, const int* __restrict__ batch,
    float* __restrict__ pooled, int n_nodes)
{
    const int j = threadIdx.x;
    const int per = (n_nodes + POOL_BLOCKS - 1) / POOL_BLOCKS;
    const int start = blockIdx.x * per;
    const int end   = min(start + per, n_nodes);
    if (start >= end) return;

    int curg = batch[start];
    float acc = 0.0f;
    for (int r = start; r < end; ++r) {
        int g = batch[r];
        if (g != curg) {
            atomicAdd(&pooled[(size_t)curg * HID + j], acc);
            acc = 0.0f;
            curg = g;
        }
        acc += h[(size_t)r * HID + j];
    }
    atomicAdd(&pooled[(size_t)curg * HID + j], acc);
}

// Pool phase 2: divide by counts (binary search on sorted batch) + final linear
__global__ __launch_bounds__(256) void pool_finalize_kernel(
    const float* __restrict__ pooled, const int* __restrict__ batch,
    const float* __restrict__ Wlin, const float* __restrict__ blin,
    float* __restrict__ out, int n_nodes)
{
    const int g = blockIdx.x;
    const int j = threadIdx.x;
    int lo = 0, hi = n_nodes;
    while (lo < hi) { int mid = (lo + hi) >> 1; if (batch[mid] < g) lo = mid + 1; else hi = mid; }
    const int start = lo;
    lo = start; hi = n_nodes;
    while (lo < hi) { int mid = (lo + hi) >> 1; if (batch[mid] < g + 1) lo = mid + 1; else hi = mid; }
    const int cnt = lo - start;

    float pv = pooled[(size_t)g * HID + j] / fmaxf((float)cnt, 1.0f);

    __shared__ float pl[HID];
    pl[j] = pv;
    __syncthreads();
    if (j < OUTC) {
        float o = blin[j];
        for (int k = 0; k < HID; ++k) o = fmaf(pl[k], Wlin[k * OUTC + j], o);
        out[g * OUTC + j] = o;
    }
}

// ---------------------------------------------------------------------------
extern "C" void kernel_launch(void* const* d_in, const int* in_sizes, int n_in,
                              void* d_out, int out_size, void* d_ws, size_t ws_size,
                              hipStream_t stream) {
    const float* x     = (const float*)d_in[0];
    const int*   ei    = (const int*)  d_in[1];   // [2, E]: row0 src, row1 dst
    const int*   batch = (const int*)  d_in[2];
    const float* W1    = (const float*)d_in[3];
    const float* b1    = (const float*)d_in[4];
    const float* W2    = (const float*)d_in[5];
    const float* b2    = (const float*)d_in[6];
    const float* Wlin  = (const float*)d_in[7];
    const float* blin  = (const float*)d_in[8];
    float* out = (float*)d_out;

    const int* src = ei;
    const int* dst = ei + EE;

    // workspace layout; h2f aliases [xs|xab|h1s] (exactly 40.96 MB, all dead
    // by the time gemm2 writes h2f)
    char* p = (char*)d_ws;
    char* region0 = p;
    u16*   xs  = (u16*)p;   p += (size_t)NN * INC * sizeof(u16);    // 10.24 MB
    u16*   xab = (u16*)p;   p += (size_t)NN * INC * sizeof(u16);    // 10.24 MB
    u16*   h1s = (u16*)p;   p += (size_t)NN * HID * sizeof(u16);    // 20.48 MB
    u16*   a2b = (u16*)p;   p += (size_t)NN * HID * sizeof(u16);    // 20.48 MB
    u16*   w1h = (u16*)p;   p += (size_t)HID * INC * sizeof(u16);
    u16*   w1l = (u16*)p;   p += (size_t)HID * INC * sizeof(u16);
    u16*   w2h = (u16*)p;   p += (size_t)HID * HID * sizeof(u16);
    u16*   w2l = (u16*)p;   p += (size_t)HID * HID * sizeof(u16);
    float* dis = (float*)p; p += (size_t)NN * sizeof(float);
    float* pooled = (float*)p; p += (size_t)GG * HID * sizeof(float);
    int* cnt    = (int*)p;  p += (size_t)NN * sizeof(int);
    int* offs   = (int*)p;  p += (size_t)(NN + 16) * sizeof(int);
    int* cursor = (int*)p;  p += (size_t)NN * sizeof(int);
    int* col    = (int*)p;  p += (size_t)EE * sizeof(int);
    float* h2f  = (float*)region0;   // 40.96 MB alias
    (void)ws_size; (void)n_in; (void)in_sizes; (void)out_size;

    const int TB = 256;
    const int nb_n = (NN + TB - 1) / TB;
    const int nb_e = (EE + TB - 1) / TB;

    // graph structure (rebuilt every call; ws is re-poisoned)
    init_kernel<<<nb_n, TB, 0, stream>>>(cnt, cursor, NN, pooled, GG * HID);
    count_kernel<<<nb_e, TB, 0, stream>>>(dst, cnt, EE);
    scan_kernel<<<1, 1024, 0, stream>>>(cnt, offs, NN);
    dis_kernel<<<nb_n, TB, 0, stream>>>(cnt, dis, NN);
    fill_kernel<<<nb_e, TB, 0, stream>>>(src, dst, offs, cursor, col, EE);

    // weight transpose + bf16 hi/lo split (tiny)
    wsplit_kernel<<<(INC * HID + TB - 1) / TB, TB, 0, stream>>>(W1, w1h, w1l, INC);
    wsplit_kernel<<<(HID * HID + TB - 1) / TB, TB, 0, stream>>>(W2, w2h, w2l, HID);

    // xs = bf16(dis .* x)
    const int total4 = NN * INC / 4;
    xs_kernel<<<(total4 + TB - 1) / TB, TB, 0, stream>>>(x, dis, xs, total4);

    dim3 ggrid((NN + BM - 1) / BM, HID / BN);

    // layer 1: xab = bf16(dis .* (xs self + gather)); h1s = bf16(dis .* relu(xab@W1 + b1))
    agg_kernel<INC><<<NN, INC, 0, stream>>>(xs, offs, col, dis, xab);
    mgemm_kernel<true><<<ggrid, 256, 0, stream>>>(xab, w1h, w1l, b1, dis,
                                                  (void*)h1s, NN, INC);

    // layer 2: a2b = bf16(dis .* (h1s self + gather)); h2f = relu(a2b@W2 + b2)
    agg_kernel<HID><<<NN, HID, 0, stream>>>(h1s, offs, col, dis, a2b);
    mgemm_kernel<false><<<ggrid, 256, 0, stream>>>(a2b, w2h, w2l, b2, dis,
                                                   (void*)h2f, NN, HID);

    // pool (two-phase) + linear
    pool_partial_kernel<<<POOL_BLOCKS, 256, 0, stream>>>(h2f, batch, pooled, NN);
    pool_finalize_kernel<<<GG, 256, 0, stream>>>(pooled, batch, Wlin, blin, out, NN);
}

// Round 5
// 426.867 us; speedup vs baseline: 1.5643x; 1.0530x over previous
//
#include <hip/hip_runtime.h>

// Problem constants (fixed by the reference):
#define NN    40000
#define EE    640000
#define INC   128
#define HID   256
#define OUTC  10
#define GG    64

typedef unsigned short u16;
typedef __attribute__((ext_vector_type(8))) short short8;   // 8 bf16 (4 VGPRs)
typedef __attribute__((ext_vector_type(4))) float f32x4;    // MFMA acc

__device__ __forceinline__ float bf2f(u16 h) {
    return __uint_as_float(((unsigned)h) << 16);
}
__device__ __forceinline__ u16 f2bf(float f) {   // round-to-nearest-even
    unsigned u = __float_as_uint(f);
    unsigned r = u + 0x7FFFu + ((u >> 16) & 1u);
    return (u16)(r >> 16);
}

// ---------------------------------------------------------------------------
// init: zero per-node int counters + pooled accumulator
__global__ void init_kernel(int* __restrict__ cnt, int* __restrict__ cursor, int n,
                            float* __restrict__ pooled, int npool) {
    int i = blockIdx.x * blockDim.x + threadIdx.x;
    if (i < n) { cnt[i] = 0; cursor[i] = 0; }
    if (i < npool) pooled[i] = 0.0f;
}

// count in-degree (excluding self loop) via int atomics
__global__ void count_kernel(const int* __restrict__ dst, int* __restrict__ cnt, int e) {
    int i = blockIdx.x * blockDim.x + threadIdx.x;
    if (i < e) atomicAdd(&cnt[dst[i]], 1);
}

// exclusive scan of cnt -> offs (single block, 1024 threads, contiguous chunks)
__global__ __launch_bounds__(1024) void scan_kernel(const int* __restrict__ cnt,
                                                    int* __restrict__ offs, int n) {
    __shared__ int buf[1024];
    const int tid = threadIdx.x;
    const int per = (n + 1023) / 1024;
    const int start = tid * per;
    const int end   = min(start + per, n);
    int s = 0;
    for (int i = start; i < end; ++i) s += cnt[i];
    buf[tid] = s;
    __syncthreads();
    for (int off = 1; off < 1024; off <<= 1) {
        int t = (tid >= off) ? buf[tid - off] : 0;
        __syncthreads();
        buf[tid] += t;
        __syncthreads();
    }
    int run = buf[tid] - s;          // exclusive prefix for this thread's chunk
    for (int i = start; i < end; ++i) { offs[i] = run; run += cnt[i]; }
    if (tid == 1023) offs[n] = buf[1023];
}

// dis[n] = rsqrt(deg) with deg = edge in-degree + 1 (self loop)
__global__ void dis_kernel(const int* __restrict__ cnt, float* __restrict__ dis, int n) {
    int i = blockIdx.x * blockDim.x + threadIdx.x;
    if (i < n) dis[i] = rsqrtf((float)(cnt[i] + 1));
}

// CSR fill: col[offs[dst]+k] = src
__global__ void fill_kernel(const int* __restrict__ src, const int* __restrict__ dst,
                            const int* __restrict__ offs, int* __restrict__ cursor,
                            int* __restrict__ col, int e) {
    int i = blockIdx.x * blockDim.x + threadIdx.x;
    if (i < e) {
        int d = dst[i];
        int pos = offs[d] + atomicAdd(&cursor[d], 1);
        col[pos] = src[i];
    }
}

// xs = bf16(dis[row] * x) -- vectorized 4 elems/thread (INC divisible by 4)
__global__ void xs_kernel(const float* __restrict__ x, const float* __restrict__ dis,
                          u16* __restrict__ xs, int total4) {
    int i = blockIdx.x * blockDim.x + threadIdx.x;
    if (i < total4) {
        float4 v = ((const float4*)x)[i];
        int row = (i << 2) >> 7;            // /INC with INC=128
        float d = dis[row];
        ushort4 o;
        o.x = f2bf(v.x * d); o.y = f2bf(v.y * d);
        o.z = f2bf(v.z * d); o.w = f2bf(v.w * d);
        ((ushort4*)xs)[i] = o;
    }
}

// W [K][N=256] fp32 -> transposed bf16 hi/lo planes Th/Tl [N=256][K]
__global__ void wsplit_kernel(const float* __restrict__ W, u16* __restrict__ Th,
                              u16* __restrict__ Tl, int K) {
    int i = blockIdx.x * blockDim.x + threadIdx.x;
    if (i < K * 256) {
        int k = i >> 8;          // /256
        int n = i & 255;
        float w = W[i];          // i == k*256 + n (row-major)
        u16 h = f2bf(w);
        float r = w - bf2f(h);
        Th[(size_t)n * K + k] = h;
        Tl[(size_t)n * K + k] = f2bf(r);
    }
}

// ---------------------------------------------------------------------------
// MFMA GEMM: C[M, 256] = A[M,K](bf16) @ (Wh+Wl)[K,256] (W stored transposed
// [256][K] bf16 hi/lo). Epilogue: v = relu(acc + bias[n]);
//   BF16OUT: store bf16(dis[m]*v), else store fp32 v.
// 128x128 tile, BK=32, 256 threads = 4 waves, each wave 4x4 16x16x32 tiles.
#define BM 128
#define BN 128
#define BK 32
#define LDP 40   // padded LDS row length (bf16 elems): 80 B -> 2-way aliasing only

template<bool BF16OUT>
__global__ __launch_bounds__(256) void mgemm_kernel(
    const u16* __restrict__ A,   // [M,K] bf16
    const u16* __restrict__ Bh,  // [256,K] bf16 (W^T hi)
    const u16* __restrict__ Bl,  // [256,K] bf16 (W^T lo)
    const float* __restrict__ bias,
    const float* __restrict__ dis,
    void* __restrict__ Cout, int M, int K)
{
    __shared__ u16 As [BM * LDP];
    __shared__ u16 Bhs[BN * LDP];
    __shared__ u16 Bls[BN * LDP];

    const int tid  = threadIdx.x;
    const int lane = tid & 63;
    const int wave = tid >> 6;
    const int ln   = lane & 15;        // col within 16x16 tile
    const int qd   = lane >> 4;        // quad: k-unit for A/B frags, row-quad for C
    const int wm   = (wave & 1) * 64;  // wave m-offset in tile
    const int wn   = (wave >> 1) * 64; // wave n-offset in tile
    const int m0   = blockIdx.x * BM;
    const int n0   = blockIdx.y * BN;

    f32x4 acc[4][4];
#pragma unroll
    for (int i = 0; i < 4; ++i)
#pragma unroll
        for (int j = 0; j < 4; ++j) acc[i][j] = (f32x4)(0.0f);

    for (int k0 = 0; k0 < K; k0 += BK) {
        // ---- stage A (128x32) and B hi/lo (128n x 32k) into LDS ----
        uint4 av[2], bhv[2], blv[2];
#pragma unroll
        for (int i = 0; i < 2; ++i) {
            int flat = tid + i * 256;          // 0..511 16B-units
            int r = flat >> 2;                 // 0..127 row
            int u = flat & 3;                  // k-unit (8 bf16)
            int grow = m0 + r;
            av[i] = make_uint4(0u, 0u, 0u, 0u);
            if (grow < M)
                av[i] = *(const uint4*)(A + (size_t)grow * K + k0 + u * 8);
            bhv[i] = *(const uint4*)(Bh + (size_t)(n0 + r) * K + k0 + u * 8);
            blv[i] = *(const uint4*)(Bl + (size_t)(n0 + r) * K + k0 + u * 8);
        }
        __syncthreads();   // previous chunk's frag reads complete
#pragma unroll
        for (int i = 0; i < 2; ++i) {
            int flat = tid + i * 256;
            int r = flat >> 2;
            int u = flat & 3;
            *(uint4*)(As  + r * LDP + u * 8) = av[i];
            *(uint4*)(Bhs + r * LDP + u * 8) = bhv[i];
            *(uint4*)(Bls + r * LDP + u * 8) = blv[i];
        }
        __syncthreads();

        // ---- fragments + MFMA ----
        short8 af[4], bfh[4], bfl[4];
#pragma unroll
        for (int t = 0; t < 4; ++t) {
            af[t]  = *(const short8*)(As  + (wm + t * 16 + ln) * LDP + qd * 8);
            bfh[t] = *(const short8*)(Bhs + (wn + t * 16 + ln) * LDP + qd * 8);
            bfl[t] = *(const short8*)(Bls + (wn + t * 16 + ln) * LDP + qd * 8);
        }
#pragma unroll
        for (int ti = 0; ti < 4; ++ti)
#pragma unroll
            for (int tj = 0; tj < 4; ++tj) {
                acc[ti][tj] = __builtin_amdgcn_mfma_f32_16x16x32_bf16(
                    af[ti], bfh[tj], acc[ti][tj], 0, 0, 0);
                acc[ti][tj] = __builtin_amdgcn_mfma_f32_16x16x32_bf16(
                    af[ti], bfl[tj], acc[ti][tj], 0, 0, 0);
            }
    }

    // ---- epilogue: C layout col=lane&15, row=qd*4+reg ----
    float bcol[4];
#pragma unroll
    for (int tj = 0; tj < 4; ++tj) bcol[tj] = bias[n0 + wn + tj * 16 + ln];

#pragma unroll
    for (int ti = 0; ti < 4; ++ti) {
#pragma unroll
        for (int r = 0; r < 4; ++r) {
            int row = m0 + wm + ti * 16 + qd * 4 + r;
            if (row < M) {
                if (BF16OUT) {
                    float dm = dis[row];
                    u16* crow = (u16*)Cout + (size_t)row * HID;
#pragma unroll
                    for (int tj = 0; tj < 4; ++tj) {
                        float v = fmaxf(acc[ti][tj][r] + bcol[tj], 0.0f);
                        crow[n0 + wn + tj * 16 + ln] = f2bf(v * dm);
                    }
                } else {
                    float* crow = (float*)Cout + (size_t)row * HID;
#pragma unroll
                    for (int tj = 0; tj < 4; ++tj) {
                        float v = fmaxf(acc[ti][tj][r] + bcol[tj], 0.0f);
                        crow[n0 + wn + tj * 16 + ln] = v;
                    }
                }
            }
        }
    }
}

// ---------------------------------------------------------------------------
// Aggregation, wave-per-node vectorized:
// out[n,:] = bf16(dis[n] * (hs[n,:] + sum_{src in in(n)} hs[src,:]))
// Lanes split into G groups of L=F/8; each lane loads uint4 = 8 bf16 (16 B).
// One wave-iteration consumes G items (item 0 = self row, then edges).
// Cross-group combine via shfl_xor; group 0 stores the packed row.
template<int F>
__global__ __launch_bounds__(256) void agg_kernel(
    const u16* __restrict__ hs, const int* __restrict__ offs,
    const int* __restrict__ col, const float* __restrict__ dis,
    u16* __restrict__ out, int n_nodes)
{
    constexpr int L = F / 8;                    // lanes per item (16 or 32)
    constexpr int G = 64 / L;                   // items per wave-iter (4 or 2)
    const int lane = threadIdx.x & 63;
    const int n    = (blockIdx.x * blockDim.x + threadIdx.x) >> 6;  // wave id
    if (n >= n_nodes) return;
    const int li = lane % L;
    const int gi = lane / L;

    const int lo = offs[n], hi = offs[n + 1];
    const int total = 1 + (hi - lo);            // self + edges

    float acc[8];
#pragma unroll
    for (int i = 0; i < 8; ++i) acc[i] = 0.0f;

    for (int base = 0; base < total; base += G) {
        int it = base + gi;
        if (it < total) {
            int idx = (it == 0) ? n : col[lo + it - 1];
            uint4 w = *(const uint4*)(hs + (size_t)idx * F + li * 8);
            unsigned uu[4] = {w.x, w.y, w.z, w.w};
#pragma unroll
            for (int q = 0; q < 4; ++q) {
                acc[2 * q]     += __uint_as_float(uu[q] << 16);
                acc[2 * q + 1] += __uint_as_float(uu[q] & 0xFFFF0000u);
            }
        }
    }

    // combine the G partial groups (lane strides L..32)
#pragma unroll
    for (int off = 32; off >= L; off >>= 1)
#pragma unroll
        for (int i = 0; i < 8; ++i)
            acc[i] += __shfl_xor(acc[i], off);

    if (gi == 0) {
        float d = dis[n];
        unsigned r[4];
#pragma unroll
        for (int q = 0; q < 4; ++q) {
            unsigned l16 = (unsigned)f2bf(acc[2 * q] * d);
            unsigned h16 = (unsigned)f2bf(acc[2 * q + 1] * d);
            r[q] = l16 | (h16 << 16);
        }
        *(uint4*)(out + (size_t)n * F + li * 8) = make_uint4(r[0], r[1], r[2], r[3]);
    }
}

// ---------------------------------------------------------------------------
// Pool phase 1: partial column sums per graph, chunked over nodes.
#define POOL_BLOCKS 320
__global__ __launch_bounds__(256) void pool_partial_kernel(
    const float* __restrict__ h, const int* __restrict__ batch,
    float* __restrict__ pooled, int n_nodes)
{
    const int j = threadIdx.x;
    const int per = (n_nodes + POOL_BLOCKS - 1) / POOL_BLOCKS;
    const int start = blockIdx.x * per;
    const int end   = min(start + per, n_nodes);
    if (start >= end) return;

    int curg = batch[start];
    float acc = 0.0f;
    for (int r = start; r < end; ++r) {
        int g = batch[r];
        if (g != curg) {
            atomicAdd(&pooled[(size_t)curg * HID + j], acc);
            acc = 0.0f;
            curg = g;
        }
        acc += h[(size_t)r * HID + j];
    }
    atomicAdd(&pooled[(size_t)curg * HID + j], acc);
}

// Pool phase 2: divide by counts (binary search on sorted batch) + final linear
__global__ __launch_bounds__(256) void pool_finalize_kernel(
    const float* __restrict__ pooled, const int* __restrict__ batch,
    const float* __restrict__ Wlin, const float* __restrict__ blin,
    float* __restrict__ out, int n_nodes)
{
    const int g = blockIdx.x;
    const int j = threadIdx.x;
    int lo = 0, hi = n_nodes;
    while (lo < hi) { int mid = (lo + hi) >> 1; if (batch[mid] < g) lo = mid + 1; else hi = mid; }
    const int start = lo;
    lo = start; hi = n_nodes;
    while (lo < hi) { int mid = (lo + hi) >> 1; if (batch[mid] < g + 1) lo = mid + 1; else hi = mid; }
    const int cnt = lo - start;

    float pv = pooled[(size_t)g * HID + j] / fmaxf((float)cnt, 1.0f);

    __shared__ float pl[HID];
    pl[j] = pv;
    __syncthreads();
    if (j < OUTC) {
        float o = blin[j];
        for (int k = 0; k < HID; ++k) o = fmaf(pl[k], Wlin[k * OUTC + j], o);
        out[g * OUTC + j] = o;
    }
}

// ---------------------------------------------------------------------------
extern "C" void kernel_launch(void* const* d_in, const int* in_sizes, int n_in,
                              void* d_out, int out_size, void* d_ws, size_t ws_size,
                              hipStream_t stream) {
    const float* x     = (const float*)d_in[0];
    const int*   ei    = (const int*)  d_in[1];   // [2, E]: row0 src, row1 dst
    const int*   batch = (const int*)  d_in[2];
    const float* W1    = (const float*)d_in[3];
    const float* b1    = (const float*)d_in[4];
    const float* W2    = (const float*)d_in[5];
    const float* b2    = (const float*)d_in[6];
    const float* Wlin  = (const float*)d_in[7];
    const float* blin  = (const float*)d_in[8];
    float* out = (float*)d_out;

    const int* src = ei;
    const int* dst = ei + EE;

    // workspace layout; h2f aliases [xs|xab|h1s] (exactly 40.96 MB, all dead
    // by the time gemm2 writes h2f)
    char* p = (char*)d_ws;
    char* region0 = p;
    u16*   xs  = (u16*)p;   p += (size_t)NN * INC * sizeof(u16);    // 10.24 MB
    u16*   xab = (u16*)p;   p += (size_t)NN * INC * sizeof(u16);    // 10.24 MB
    u16*   h1s = (u16*)p;   p += (size_t)NN * HID * sizeof(u16);    // 20.48 MB
    u16*   a2b = (u16*)p;   p += (size_t)NN * HID * sizeof(u16);    // 20.48 MB
    u16*   w1h = (u16*)p;   p += (size_t)HID * INC * sizeof(u16);
    u16*   w1l = (u16*)p;   p += (size_t)HID * INC * sizeof(u16);
    u16*   w2h = (u16*)p;   p += (size_t)HID * HID * sizeof(u16);
    u16*   w2l = (u16*)p;   p += (size_t)HID * HID * sizeof(u16);
    float* dis = (float*)p; p += (size_t)NN * sizeof(float);
    float* pooled = (float*)p; p += (size_t)GG * HID * sizeof(float);
    int* cnt    = (int*)p;  p += (size_t)NN * sizeof(int);
    int* offs   = (int*)p;  p += (size_t)(NN + 16) * sizeof(int);
    int* cursor = (int*)p;  p += (size_t)NN * sizeof(int);
    int* col    = (int*)p;  p += (size_t)EE * sizeof(int);
    float* h2f  = (float*)region0;   // 40.96 MB alias
    (void)ws_size; (void)n_in; (void)in_sizes; (void)out_size;

    const int TB = 256;
    const int nb_n = (NN + TB - 1) / TB;
    const int nb_e = (EE + TB - 1) / TB;

    // graph structure (rebuilt every call; ws is re-poisoned)
    init_kernel<<<nb_n, TB, 0, stream>>>(cnt, cursor, NN, pooled, GG * HID);
    count_kernel<<<nb_e, TB, 0, stream>>>(dst, cnt, EE);
    scan_kernel<<<1, 1024, 0, stream>>>(cnt, offs, NN);
    dis_kernel<<<nb_n, TB, 0, stream>>>(cnt, dis, NN);
    fill_kernel<<<nb_e, TB, 0, stream>>>(src, dst, offs, cursor, col, EE);

    // weight transpose + bf16 hi/lo split (tiny)
    wsplit_kernel<<<(INC * HID + TB - 1) / TB, TB, 0, stream>>>(W1, w1h, w1l, INC);
    wsplit_kernel<<<(HID * HID + TB - 1) / TB, TB, 0, stream>>>(W2, w2h, w2l, HID);

    // xs = bf16(dis .* x)
    const int total4 = NN * INC / 4;
    xs_kernel<<<(total4 + TB - 1) / TB, TB, 0, stream>>>(x, dis, xs, total4);

    dim3 ggrid((NN + BM - 1) / BM, HID / BN);
    const int agg_blocks = (NN * 64 + TB - 1) / TB;   // one wave per node

    // layer 1: xab = bf16(dis .* (xs self + gather)); h1s = bf16(dis .* relu(xab@W1 + b1))
    agg_kernel<INC><<<agg_blocks, TB, 0, stream>>>(xs, offs, col, dis, xab, NN);
    mgemm_kernel<true><<<ggrid, 256, 0, stream>>>(xab, w1h, w1l, b1, dis,
                                                  (void*)h1s, NN, INC);

    // layer 2: a2b = bf16(dis .* (h1s self + gather)); h2f = relu(a2b@W2 + b2)
    agg_kernel<HID><<<agg_blocks, TB, 0, stream>>>(h1s, offs, col, dis, a2b, NN);
    mgemm_kernel<false><<<ggrid, 256, 0, stream>>>(a2b, w2h, w2l, b2, dis,
                                                   (void*)h2f, NN, HID);

    // pool (two-phase) + linear
    pool_partial_kernel<<<POOL_BLOCKS, 256, 0, stream>>>(h2f, batch, pooled, NN);
    pool_finalize_kernel<<<GG, 256, 0, stream>>>(pooled, batch, Wlin, blin, out, NN);
}

// Round 6
// 361.259 us; speedup vs baseline: 1.8484x; 1.1816x over previous
//
#include <hip/hip_runtime.h>

// Problem constants (fixed by the reference):
#define NN    40000
#define EE    640000
#define INC   128
#define HID   256
#define OUTC  10
#define GG    64

typedef unsigned short u16;
typedef __attribute__((ext_vector_type(8))) short short8;   // 8 bf16 (4 VGPRs)
typedef __attribute__((ext_vector_type(4))) float f32x4;    // MFMA acc

__device__ __forceinline__ float bf2f(u16 h) {
    return __uint_as_float(((unsigned)h) << 16);
}
__device__ __forceinline__ u16 f2bf(float f) {   // round-to-nearest-even
    unsigned u = __float_as_uint(f);
    unsigned r = u + 0x7FFFu + ((u >> 16) & 1u);
    return (u16)(r >> 16);
}

// ---------------------------------------------------------------------------
// init: zero per-node int counters + pooled accumulator
__global__ void init_kernel(int* __restrict__ cnt, int* __restrict__ cursor, int n,
                            float* __restrict__ pooled, int npool) {
    int i = blockIdx.x * blockDim.x + threadIdx.x;
    if (i < n) { cnt[i] = 0; cursor[i] = 0; }
    if (i < npool) pooled[i] = 0.0f;
}

// count in-degree (excluding self loop) via int atomics
__global__ void count_kernel(const int* __restrict__ dst, int* __restrict__ cnt, int e) {
    int i = blockIdx.x * blockDim.x + threadIdx.x;
    if (i < e) atomicAdd(&cnt[dst[i]], 1);
}

// ---------------------------------------------------------------------------
// Multi-block exclusive scan of cnt[0..n) -> offs, 1 elem/thread, coalesced.
// scan1: per-block exclusive prefix (pre) + block sums (bsum); also dis[i].
#define SCAN_B 256
__global__ __launch_bounds__(SCAN_B) void scan1_kernel(
    const int* __restrict__ cnt, int* __restrict__ pre, int* __restrict__ bsum,
    float* __restrict__ dis, int n)
{
    __shared__ int buf[SCAN_B];
    const int t = threadIdx.x;
    const int i = blockIdx.x * SCAN_B + t;
    int v = (i < n) ? cnt[i] : 0;
    buf[t] = v;
    __syncthreads();
#pragma unroll
    for (int off = 1; off < SCAN_B; off <<= 1) {
        int add = (t >= off) ? buf[t - off] : 0;
        __syncthreads();
        buf[t] += add;
        __syncthreads();
    }
    if (i < n) {
        pre[i] = buf[t] - v;            // exclusive in-block prefix
        dis[i] = rsqrtf((float)(v + 1));
    }
    if (t == SCAN_B - 1) bsum[blockIdx.x] = buf[t];
}

// scan2: exclusive scan of block sums (nb <= 256), writes offs[n] = total.
__global__ __launch_bounds__(SCAN_B) void scan2_kernel(
    const int* __restrict__ bsum, int* __restrict__ boff,
    int* __restrict__ offs, int nb, int n)
{
    __shared__ int buf[SCAN_B];
    const int t = threadIdx.x;
    int v = (t < nb) ? bsum[t] : 0;
    buf[t] = v;
    __syncthreads();
#pragma unroll
    for (int off = 1; off < SCAN_B; off <<= 1) {
        int add = (t >= off) ? buf[t - off] : 0;
        __syncthreads();
        buf[t] += add;
        __syncthreads();
    }
    if (t < nb) boff[t] = buf[t] - v;
    if (t == nb - 1) offs[n] = buf[t];
}

// scan3: offs[i] = pre[i] + boff[blk]
__global__ __launch_bounds__(SCAN_B) void scan3_kernel(
    const int* __restrict__ pre, const int* __restrict__ boff,
    int* __restrict__ offs, int n)
{
    const int i = blockIdx.x * SCAN_B + threadIdx.x;
    if (i < n) offs[i] = pre[i] + boff[blockIdx.x];
}

// CSR fill: col[offs[dst]+k] = src
__global__ void fill_kernel(const int* __restrict__ src, const int* __restrict__ dst,
                            const int* __restrict__ offs, int* __restrict__ cursor,
                            int* __restrict__ col, int e) {
    int i = blockIdx.x * blockDim.x + threadIdx.x;
    if (i < e) {
        int d = dst[i];
        int pos = offs[d] + atomicAdd(&cursor[d], 1);
        col[pos] = src[i];
    }
}

// xs = bf16(dis[row] * x) -- vectorized 4 elems/thread (INC divisible by 4)
__global__ void xs_kernel(const float* __restrict__ x, const float* __restrict__ dis,
                          u16* __restrict__ xs, int total4) {
    int i = blockIdx.x * blockDim.x + threadIdx.x;
    if (i < total4) {
        float4 v = ((const float4*)x)[i];
        int row = (i << 2) >> 7;            // /INC with INC=128
        float d = dis[row];
        ushort4 o;
        o.x = f2bf(v.x * d); o.y = f2bf(v.y * d);
        o.z = f2bf(v.z * d); o.w = f2bf(v.w * d);
        ((ushort4*)xs)[i] = o;
    }
}

// Both weights: W [K][256] fp32 -> transposed bf16 hi/lo planes [256][K].
// Flat index < INC*HID handles W1, rest handles W2.
__global__ void wsplit_kernel(const float* __restrict__ W1, u16* __restrict__ T1h,
                              u16* __restrict__ T1l,
                              const float* __restrict__ W2, u16* __restrict__ T2h,
                              u16* __restrict__ T2l) {
    int i = blockIdx.x * blockDim.x + threadIdx.x;
    const float* W; u16 *Th, *Tl; int K, idx;
    if (i < INC * HID) { W = W1; Th = T1h; Tl = T1l; K = INC; idx = i; }
    else if (i < INC * HID + HID * HID) {
        W = W2; Th = T2h; Tl = T2l; K = HID; idx = i - INC * HID;
    } else return;
    int k = idx >> 8;          // /256
    int n = idx & 255;
    float w = W[idx];          // idx == k*256 + n (row-major)
    u16 h = f2bf(w);
    float r = w - bf2f(h);
    Th[(size_t)n * K + k] = h;
    Tl[(size_t)n * K + k] = f2bf(r);
}

// ---------------------------------------------------------------------------
// MFMA GEMM: C[M, 256] = A[M,K](bf16) @ (Wh+Wl)[K,256] (W stored transposed
// [256][K] bf16 hi/lo). Epilogue: v = relu(acc + bias[n]);
//   BF16OUT: store bf16(dis[m]*v), else store fp32 v.
// 128x128 tile, BK=32, 256 threads = 4 waves, each wave 4x4 16x16x32 tiles.
#define BM 128
#define BN 128
#define BK 32
#define LDP 40   // padded LDS row length (bf16 elems): 80 B -> 2-way aliasing only

template<bool BF16OUT>
__global__ __launch_bounds__(256) void mgemm_kernel(
    const u16* __restrict__ A,   // [M,K] bf16
    const u16* __restrict__ Bh,  // [256,K] bf16 (W^T hi)
    const u16* __restrict__ Bl,  // [256,K] bf16 (W^T lo)
    const float* __restrict__ bias,
    const float* __restrict__ dis,
    void* __restrict__ Cout, int M, int K)
{
    __shared__ u16 As [BM * LDP];
    __shared__ u16 Bhs[BN * LDP];
    __shared__ u16 Bls[BN * LDP];

    const int tid  = threadIdx.x;
    const int lane = tid & 63;
    const int wave = tid >> 6;
    const int ln   = lane & 15;        // col within 16x16 tile
    const int qd   = lane >> 4;        // quad: k-unit for A/B frags, row-quad for C
    const int wm   = (wave & 1) * 64;  // wave m-offset in tile
    const int wn   = (wave >> 1) * 64; // wave n-offset in tile
    const int m0   = blockIdx.x * BM;
    const int n0   = blockIdx.y * BN;

    f32x4 acc[4][4];
#pragma unroll
    for (int i = 0; i < 4; ++i)
#pragma unroll
        for (int j = 0; j < 4; ++j) acc[i][j] = (f32x4)(0.0f);

    for (int k0 = 0; k0 < K; k0 += BK) {
        // ---- stage A (128x32) and B hi/lo (128n x 32k) into LDS ----
        uint4 av[2], bhv[2], blv[2];
#pragma unroll
        for (int i = 0; i < 2; ++i) {
            int flat = tid + i * 256;          // 0..511 16B-units
            int r = flat >> 2;                 // 0..127 row
            int u = flat & 3;                  // k-unit (8 bf16)
            int grow = m0 + r;
            av[i] = make_uint4(0u, 0u, 0u, 0u);
            if (grow < M)
                av[i] = *(const uint4*)(A + (size_t)grow * K + k0 + u * 8);
            bhv[i] = *(const uint4*)(Bh + (size_t)(n0 + r) * K + k0 + u * 8);
            blv[i] = *(const uint4*)(Bl + (size_t)(n0 + r) * K + k0 + u * 8);
        }
        __syncthreads();   // previous chunk's frag reads complete
#pragma unroll
        for (int i = 0; i < 2; ++i) {
            int flat = tid + i * 256;
            int r = flat >> 2;
            int u = flat & 3;
            *(uint4*)(As  + r * LDP + u * 8) = av[i];
            *(uint4*)(Bhs + r * LDP + u * 8) = bhv[i];
            *(uint4*)(Bls + r * LDP + u * 8) = blv[i];
        }
        __syncthreads();

        // ---- fragments + MFMA ----
        short8 af[4], bfh[4], bfl[4];
#pragma unroll
        for (int t = 0; t < 4; ++t) {
            af[t]  = *(const short8*)(As  + (wm + t * 16 + ln) * LDP + qd * 8);
            bfh[t] = *(const short8*)(Bhs + (wn + t * 16 + ln) * LDP + qd * 8);
            bfl[t] = *(const short8*)(Bls + (wn + t * 16 + ln) * LDP + qd * 8);
        }
#pragma unroll
        for (int ti = 0; ti < 4; ++ti)
#pragma unroll
            for (int tj = 0; tj < 4; ++tj) {
                acc[ti][tj] = __builtin_amdgcn_mfma_f32_16x16x32_bf16(
                    af[ti], bfh[tj], acc[ti][tj], 0, 0, 0);
                acc[ti][tj] = __builtin_amdgcn_mfma_f32_16x16x32_bf16(
                    af[ti], bfl[tj], acc[ti][tj], 0, 0, 0);
            }
    }

    // ---- epilogue: C layout col=lane&15, row=qd*4+reg ----
    float bcol[4];
#pragma unroll
    for (int tj = 0; tj < 4; ++tj) bcol[tj] = bias[n0 + wn + tj * 16 + ln];

#pragma unroll
    for (int ti = 0; ti < 4; ++ti) {
#pragma unroll
        for (int r = 0; r < 4; ++r) {
            int row = m0 + wm + ti * 16 + qd * 4 + r;
            if (row < M) {
                if (BF16OUT) {
                    float dm = dis[row];
                    u16* crow = (u16*)Cout + (size_t)row * HID;
#pragma unroll
                    for (int tj = 0; tj < 4; ++tj) {
                        float v = fmaxf(acc[ti][tj][r] + bcol[tj], 0.0f);
                        crow[n0 + wn + tj * 16 + ln] = f2bf(v * dm);
                    }
                } else {
                    float* crow = (float*)Cout + (size_t)row * HID;
#pragma unroll
                    for (int tj = 0; tj < 4; ++tj) {
                        float v = fmaxf(acc[ti][tj][r] + bcol[tj], 0.0f);
                        crow[n0 + wn + tj * 16 + ln] = v;
                    }
                }
            }
        }
    }
}

// ---------------------------------------------------------------------------
// Aggregation, wave-per-node vectorized:
// out[n,:] = bf16(dis[n] * (hs[n,:] + sum_{src in in(n)} hs[src,:]))
// Lanes split into G groups of L=F/8; each lane loads uint4 = 8 bf16 (16 B).
// One wave-iteration consumes G items (item 0 = self row, then edges).
// Cross-group combine via shfl_xor; group 0 stores the packed row.
template<int F>
__global__ __launch_bounds__(256) void agg_kernel(
    const u16* __restrict__ hs, const int* __restrict__ offs,
    const int* __restrict__ col, const float* __restrict__ dis,
    u16* __restrict__ out, int n_nodes)
{
    constexpr int L = F / 8;                    // lanes per item (16 or 32)
    constexpr int G = 64 / L;                   // items per wave-iter (4 or 2)
    const int lane = threadIdx.x & 63;
    const int n    = (blockIdx.x * blockDim.x + threadIdx.x) >> 6;  // wave id
    if (n >= n_nodes) return;
    const int li = lane % L;
    const int gi = lane / L;

    const int lo = offs[n], hi = offs[n + 1];
    const int total = 1 + (hi - lo);            // self + edges

    float acc[8];
#pragma unroll
    for (int i = 0; i < 8; ++i) acc[i] = 0.0f;

    for (int base = 0; base < total; base += G) {
        int it = base + gi;
        if (it < total) {
            int idx = (it == 0) ? n : col[lo + it - 1];
            uint4 w = *(const uint4*)(hs + (size_t)idx * F + li * 8);
            unsigned uu[4] = {w.x, w.y, w.z, w.w};
#pragma unroll
            for (int q = 0; q < 4; ++q) {
                acc[2 * q]     += __uint_as_float(uu[q] << 16);
                acc[2 * q + 1] += __uint_as_float(uu[q] & 0xFFFF0000u);
            }
        }
    }

    // combine the G partial groups (lane strides L..32)
#pragma unroll
    for (int off = 32; off >= L; off >>= 1)
#pragma unroll
        for (int i = 0; i < 8; ++i)
            acc[i] += __shfl_xor(acc[i], off);

    if (gi == 0) {
        float d = dis[n];
        unsigned r[4];
#pragma unroll
        for (int q = 0; q < 4; ++q) {
            unsigned l16 = (unsigned)f2bf(acc[2 * q] * d);
            unsigned h16 = (unsigned)f2bf(acc[2 * q + 1] * d);
            r[q] = l16 | (h16 << 16);
        }
        *(uint4*)(out + (size_t)n * F + li * 8) = make_uint4(r[0], r[1], r[2], r[3]);
    }
}

// ---------------------------------------------------------------------------
// Pool phase 1: partial column sums per graph, chunked over nodes.
#define POOL_BLOCKS 320
__global__ __launch_bounds__(256) void pool_partial_kernel(
    const float* __restrict__ h, const int* __restrict__ batch,
    float* __restrict__ pooled, int n_nodes)
{
    const int j = threadIdx.x;
    const int per = (n_nodes + POOL_BLOCKS - 1) / POOL_BLOCKS;
    const int start = blockIdx.x * per;
    const int end   = min(start + per, n_nodes);
    if (start >= end) return;

    int curg = batch[start];
    float acc = 0.0f;
    for (int r = start; r < end; ++r) {
        int g = batch[r];
        if (g != curg) {
            atomicAdd(&pooled[(size_t)curg * HID + j], acc);
            acc = 0.0f;
            curg = g;
        }
        acc += h[(size_t)r * HID + j];
    }
    atomicAdd(&pooled[(size_t)curg * HID + j], acc);
}

// Pool phase 2: divide by counts (binary search on sorted batch) + final linear
__global__ __launch_bounds__(256) void pool_finalize_kernel(
    const float* __restrict__ pooled, const int* __restrict__ batch,
    const float* __restrict__ Wlin, const float* __restrict__ blin,
    float* __restrict__ out, int n_nodes)
{
    const int g = blockIdx.x;
    const int j = threadIdx.x;
    int lo = 0, hi = n_nodes;
    while (lo < hi) { int mid = (lo + hi) >> 1; if (batch[mid] < g) lo = mid + 1; else hi = mid; }
    const int start = lo;
    lo = start; hi = n_nodes;
    while (lo < hi) { int mid = (lo + hi) >> 1; if (batch[mid] < g + 1) lo = mid + 1; else hi = mid; }
    const int cnt = lo - start;

    float pv = pooled[(size_t)g * HID + j] / fmaxf((float)cnt, 1.0f);

    __shared__ float pl[HID];
    pl[j] = pv;
    __syncthreads();
    if (j < OUTC) {
        float o = blin[j];
        for (int k = 0; k < HID; ++k) o = fmaf(pl[k], Wlin[k * OUTC + j], o);
        out[g * OUTC + j] = o;
    }
}

// ---------------------------------------------------------------------------
extern "C" void kernel_launch(void* const* d_in, const int* in_sizes, int n_in,
                              void* d_out, int out_size, void* d_ws, size_t ws_size,
                              hipStream_t stream) {
    const float* x     = (const float*)d_in[0];
    const int*   ei    = (const int*)  d_in[1];   // [2, E]: row0 src, row1 dst
    const int*   batch = (const int*)  d_in[2];
    const float* W1    = (const float*)d_in[3];
    const float* b1    = (const float*)d_in[4];
    const float* W2    = (const float*)d_in[5];
    const float* b2    = (const float*)d_in[6];
    const float* Wlin  = (const float*)d_in[7];
    const float* blin  = (const float*)d_in[8];
    float* out = (float*)d_out;

    const int* src = ei;
    const int* dst = ei + EE;

    // workspace layout; h2f aliases [xs|xab|h1s] (exactly 40.96 MB, all dead
    // by the time gemm2 writes h2f)
    char* p = (char*)d_ws;
    char* region0 = p;
    u16*   xs  = (u16*)p;   p += (size_t)NN * INC * sizeof(u16);    // 10.24 MB
    u16*   xab = (u16*)p;   p += (size_t)NN * INC * sizeof(u16);    // 10.24 MB
    u16*   h1s = (u16*)p;   p += (size_t)NN * HID * sizeof(u16);    // 20.48 MB
    u16*   a2b = (u16*)p;   p += (size_t)NN * HID * sizeof(u16);    // 20.48 MB
    u16*   w1h = (u16*)p;   p += (size_t)HID * INC * sizeof(u16);
    u16*   w1l = (u16*)p;   p += (size_t)HID * INC * sizeof(u16);
    u16*   w2h = (u16*)p;   p += (size_t)HID * HID * sizeof(u16);
    u16*   w2l = (u16*)p;   p += (size_t)HID * HID * sizeof(u16);
    float* dis = (float*)p; p += (size_t)NN * sizeof(float);
    float* pooled = (float*)p; p += (size_t)GG * HID * sizeof(float);
    int* cnt    = (int*)p;  p += (size_t)NN * sizeof(int);
    int* offs   = (int*)p;  p += (size_t)(NN + 16) * sizeof(int);
    int* cursor = (int*)p;  p += (size_t)NN * sizeof(int);
    int* col    = (int*)p;  p += (size_t)EE * sizeof(int);
    int* pre    = (int*)p;  p += (size_t)NN * sizeof(int);
    int* bsum   = (int*)p;  p += 512 * sizeof(int);
    int* boff   = (int*)p;  p += 512 * sizeof(int);
    float* h2f  = (float*)region0;   // 40.96 MB alias
    (void)ws_size; (void)n_in; (void)in_sizes; (void)out_size;

    const int TB = 256;
    const int nb_n = (NN + TB - 1) / TB;      // 157
    const int nb_e = (EE + TB - 1) / TB;

    // graph structure (rebuilt every call; ws is re-poisoned)
    init_kernel<<<nb_n, TB, 0, stream>>>(cnt, cursor, NN, pooled, GG * HID);
    count_kernel<<<nb_e, TB, 0, stream>>>(dst, cnt, EE);
    scan1_kernel<<<nb_n, SCAN_B, 0, stream>>>(cnt, pre, bsum, dis, NN);
    scan2_kernel<<<1, SCAN_B, 0, stream>>>(bsum, boff, offs, nb_n, NN);
    scan3_kernel<<<nb_n, SCAN_B, 0, stream>>>(pre, boff, offs, NN);
    fill_kernel<<<nb_e, TB, 0, stream>>>(src, dst, offs, cursor, col, EE);

    // weight transpose + bf16 hi/lo split (both weights, one launch)
    const int wtot = INC * HID + HID * HID;
    wsplit_kernel<<<(wtot + TB - 1) / TB, TB, 0, stream>>>(W1, w1h, w1l, W2, w2h, w2l);

    // xs = bf16(dis .* x)
    const int total4 = NN * INC / 4;
    xs_kernel<<<(total4 + TB - 1) / TB, TB, 0, stream>>>(x, dis, xs, total4);

    dim3 ggrid((NN + BM - 1) / BM, HID / BN);
    const int agg_blocks = (NN * 64 + TB - 1) / TB;   // one wave per node

    // layer 1: xab = bf16(dis .* (xs self + gather)); h1s = bf16(dis .* relu(xab@W1 + b1))
    agg_kernel<INC><<<agg_blocks, TB, 0, stream>>>(xs, offs, col, dis, xab, NN);
    mgemm_kernel<true><<<ggrid, 256, 0, stream>>>(xab, w1h, w1l, b1, dis,
                                                  (void*)h1s, NN, INC);

    // layer 2: a2b = bf16(dis .* (h1s self + gather)); h2f = relu(a2b@W2 + b2)
    agg_kernel<HID><<<agg_blocks, TB, 0, stream>>>(h1s, offs, col, dis, a2b, NN);
    mgemm_kernel<false><<<ggrid, 256, 0, stream>>>(a2b, w2h, w2l, b2, dis,
                                                   (void*)h2f, NN, HID);

    // pool (two-phase) + linear
    pool_partial_kernel<<<POOL_BLOCKS, 256, 0, stream>>>(h2f, batch, pooled, NN);
    pool_finalize_kernel<<<GG, 256, 0, stream>>>(pooled, batch, Wlin, blin, out, NN);
}

// Round 7
// 350.786 us; speedup vs baseline: 1.9036x; 1.0299x over previous
//
#include <hip/hip_runtime.h>

// Problem constants (fixed by the reference):
#define NN    40000
#define EE    640000
#define INC   128
#define HID   256
#define OUTC  10
#define GG    64

typedef unsigned short u16;
typedef __attribute__((ext_vector_type(8))) short short8;   // 8 bf16 (4 VGPRs)
typedef __attribute__((ext_vector_type(4))) float f32x4;    // MFMA acc

__device__ __forceinline__ float bf2f(u16 h) {
    return __uint_as_float(((unsigned)h) << 16);
}
__device__ __forceinline__ u16 f2bf(float f) {   // round-to-nearest-even
    unsigned u = __float_as_uint(f);
    unsigned r = u + 0x7FFFu + ((u >> 16) & 1u);
    return (u16)(r >> 16);
}

// ---------------------------------------------------------------------------
// init: zero per-node int counters + pooled accumulator
__global__ void init_kernel(int* __restrict__ cnt, int* __restrict__ cursor, int n,
                            float* __restrict__ pooled, int npool) {
    int i = blockIdx.x * blockDim.x + threadIdx.x;
    if (i < n) { cnt[i] = 0; cursor[i] = 0; }
    if (i < npool) pooled[i] = 0.0f;
}

// count in-degree (excluding self loop) via int atomics
__global__ void count_kernel(const int* __restrict__ dst, int* __restrict__ cnt, int e) {
    int i = blockIdx.x * blockDim.x + threadIdx.x;
    if (i < e) atomicAdd(&cnt[dst[i]], 1);
}

// ---------------------------------------------------------------------------
// Multi-block exclusive scan of cnt[0..n) -> offs, 1 elem/thread, coalesced.
// scan1: per-block exclusive prefix (pre) + block sums (bsum); also dis[i].
#define SCAN_B 256
__global__ __launch_bounds__(SCAN_B) void scan1_kernel(
    const int* __restrict__ cnt, int* __restrict__ pre, int* __restrict__ bsum,
    float* __restrict__ dis, int n)
{
    __shared__ int buf[SCAN_B];
    const int t = threadIdx.x;
    const int i = blockIdx.x * SCAN_B + t;
    int v = (i < n) ? cnt[i] : 0;
    buf[t] = v;
    __syncthreads();
#pragma unroll
    for (int off = 1; off < SCAN_B; off <<= 1) {
        int add = (t >= off) ? buf[t - off] : 0;
        __syncthreads();
        buf[t] += add;
        __syncthreads();
    }
    if (i < n) {
        pre[i] = buf[t] - v;            // exclusive in-block prefix
        dis[i] = rsqrtf((float)(v + 1));
    }
    if (t == SCAN_B - 1) bsum[blockIdx.x] = buf[t];
}

// scan2: exclusive scan of block sums (nb <= 256), writes offs[n] = total.
__global__ __launch_bounds__(SCAN_B) void scan2_kernel(
    const int* __restrict__ bsum, int* __restrict__ boff,
    int* __restrict__ offs, int nb, int n)
{
    __shared__ int buf[SCAN_B];
    const int t = threadIdx.x;
    int v = (t < nb) ? bsum[t] : 0;
    buf[t] = v;
    __syncthreads();
#pragma unroll
    for (int off = 1; off < SCAN_B; off <<= 1) {
        int add = (t >= off) ? buf[t - off] : 0;
        __syncthreads();
        buf[t] += add;
        __syncthreads();
    }
    if (t < nb) boff[t] = buf[t] - v;
    if (t == nb - 1) offs[n] = buf[t];
}

// scan3: offs[i] = pre[i] + boff[blk]
__global__ __launch_bounds__(SCAN_B) void scan3_kernel(
    const int* __restrict__ pre, const int* __restrict__ boff,
    int* __restrict__ offs, int n)
{
    const int i = blockIdx.x * SCAN_B + threadIdx.x;
    if (i < n) offs[i] = pre[i] + boff[blockIdx.x];
}

// CSR fill: col[offs[dst]+k] = src
__global__ void fill_kernel(const int* __restrict__ src, const int* __restrict__ dst,
                            const int* __restrict__ offs, int* __restrict__ cursor,
                            int* __restrict__ col, int e) {
    int i = blockIdx.x * blockDim.x + threadIdx.x;
    if (i < e) {
        int d = dst[i];
        int pos = offs[d] + atomicAdd(&cursor[d], 1);
        col[pos] = src[i];
    }
}

// xs = bf16(dis[row] * x) -- vectorized 4 elems/thread (INC divisible by 4)
__global__ void xs_kernel(const float* __restrict__ x, const float* __restrict__ dis,
                          u16* __restrict__ xs, int total4) {
    int i = blockIdx.x * blockDim.x + threadIdx.x;
    if (i < total4) {
        float4 v = ((const float4*)x)[i];
        int row = (i << 2) >> 7;            // /INC with INC=128
        float d = dis[row];
        ushort4 o;
        o.x = f2bf(v.x * d); o.y = f2bf(v.y * d);
        o.z = f2bf(v.z * d); o.w = f2bf(v.w * d);
        ((ushort4*)xs)[i] = o;
    }
}

// Both weights: W [K][256] fp32 -> transposed bf16 hi/lo planes [256][K].
// Flat index < INC*HID handles W1, rest handles W2.
__global__ void wsplit_kernel(const float* __restrict__ W1, u16* __restrict__ T1h,
                              u16* __restrict__ T1l,
                              const float* __restrict__ W2, u16* __restrict__ T2h,
                              u16* __restrict__ T2l) {
    int i = blockIdx.x * blockDim.x + threadIdx.x;
    const float* W; u16 *Th, *Tl; int K, idx;
    if (i < INC * HID) { W = W1; Th = T1h; Tl = T1l; K = INC; idx = i; }
    else if (i < INC * HID + HID * HID) {
        W = W2; Th = T2h; Tl = T2l; K = HID; idx = i - INC * HID;
    } else return;
    int k = idx >> 8;          // /256
    int n = idx & 255;
    float w = W[idx];          // idx == k*256 + n (row-major)
    u16 h = f2bf(w);
    float r = w - bf2f(h);
    Th[(size_t)n * K + k] = h;
    Tl[(size_t)n * K + k] = f2bf(r);
}

// ---------------------------------------------------------------------------
// MFMA GEMM: C[M, 256] = A[M,K](bf16) @ (Wh+Wl)[K,256] (W stored transposed
// [256][K] bf16 hi/lo). Epilogue: v = relu(acc + bias[n]);
//   BF16OUT: store bf16(dis[m]*v), else store fp32 v.
// 128x128 tile, BK=32, 256 threads = 4 waves, each wave 4x4 16x16x32 tiles.
#define BM 128
#define BN 128
#define BK 32
#define LDP 40   // padded LDS row length (bf16 elems): 80 B -> 2-way aliasing only

template<bool BF16OUT>
__global__ __launch_bounds__(256) void mgemm_kernel(
    const u16* __restrict__ A,   // [M,K] bf16
    const u16* __restrict__ Bh,  // [256,K] bf16 (W^T hi)
    const u16* __restrict__ Bl,  // [256,K] bf16 (W^T lo)
    const float* __restrict__ bias,
    const float* __restrict__ dis,
    void* __restrict__ Cout, int M, int K)
{
    __shared__ u16 As [BM * LDP];
    __shared__ u16 Bhs[BN * LDP];
    __shared__ u16 Bls[BN * LDP];

    const int tid  = threadIdx.x;
    const int lane = tid & 63;
    const int wave = tid >> 6;
    const int ln   = lane & 15;        // col within 16x16 tile
    const int qd   = lane >> 4;        // quad: k-unit for A/B frags, row-quad for C
    const int wm   = (wave & 1) * 64;  // wave m-offset in tile
    const int wn   = (wave >> 1) * 64; // wave n-offset in tile
    const int m0   = blockIdx.x * BM;
    const int n0   = blockIdx.y * BN;

    f32x4 acc[4][4];
#pragma unroll
    for (int i = 0; i < 4; ++i)
#pragma unroll
        for (int j = 0; j < 4; ++j) acc[i][j] = (f32x4)(0.0f);

    for (int k0 = 0; k0 < K; k0 += BK) {
        // ---- stage A (128x32) and B hi/lo (128n x 32k) into LDS ----
        uint4 av[2], bhv[2], blv[2];
#pragma unroll
        for (int i = 0; i < 2; ++i) {
            int flat = tid + i * 256;          // 0..511 16B-units
            int r = flat >> 2;                 // 0..127 row
            int u = flat & 3;                  // k-unit (8 bf16)
            int grow = m0 + r;
            av[i] = make_uint4(0u, 0u, 0u, 0u);
            if (grow < M)
                av[i] = *(const uint4*)(A + (size_t)grow * K + k0 + u * 8);
            bhv[i] = *(const uint4*)(Bh + (size_t)(n0 + r) * K + k0 + u * 8);
            blv[i] = *(const uint4*)(Bl + (size_t)(n0 + r) * K + k0 + u * 8);
        }
        __syncthreads();   // previous chunk's frag reads complete
#pragma unroll
        for (int i = 0; i < 2; ++i) {
            int flat = tid + i * 256;
            int r = flat >> 2;
            int u = flat & 3;
            *(uint4*)(As  + r * LDP + u * 8) = av[i];
            *(uint4*)(Bhs + r * LDP + u * 8) = bhv[i];
            *(uint4*)(Bls + r * LDP + u * 8) = blv[i];
        }
        __syncthreads();

        // ---- fragments + MFMA ----
        short8 af[4], bfh[4], bfl[4];
#pragma unroll
        for (int t = 0; t < 4; ++t) {
            af[t]  = *(const short8*)(As  + (wm + t * 16 + ln) * LDP + qd * 8);
            bfh[t] = *(const short8*)(Bhs + (wn + t * 16 + ln) * LDP + qd * 8);
            bfl[t] = *(const short8*)(Bls + (wn + t * 16 + ln) * LDP + qd * 8);
        }
#pragma unroll
        for (int ti = 0; ti < 4; ++ti)
#pragma unroll
            for (int tj = 0; tj < 4; ++tj) {
                acc[ti][tj] = __builtin_amdgcn_mfma_f32_16x16x32_bf16(
                    af[ti], bfh[tj], acc[ti][tj], 0, 0, 0);
                acc[ti][tj] = __builtin_amdgcn_mfma_f32_16x16x32_bf16(
                    af[ti], bfl[tj], acc[ti][tj], 0, 0, 0);
            }
    }

    // ---- epilogue: C layout col=lane&15, row=qd*4+reg ----
    float bcol[4];
#pragma unroll
    for (int tj = 0; tj < 4; ++tj) bcol[tj] = bias[n0 + wn + tj * 16 + ln];

#pragma unroll
    for (int ti = 0; ti < 4; ++ti) {
#pragma unroll
        for (int r = 0; r < 4; ++r) {
            int row = m0 + wm + ti * 16 + qd * 4 + r;
            if (row < M) {
                if (BF16OUT) {
                    float dm = dis[row];
                    u16* crow = (u16*)Cout + (size_t)row * HID;
#pragma unroll
                    for (int tj = 0; tj < 4; ++tj) {
                        float v = fmaxf(acc[ti][tj][r] + bcol[tj], 0.0f);
                        crow[n0 + wn + tj * 16 + ln] = f2bf(v * dm);
                    }
                } else {
                    float* crow = (float*)Cout + (size_t)row * HID;
#pragma unroll
                    for (int tj = 0; tj < 4; ++tj) {
                        float v = fmaxf(acc[ti][tj][r] + bcol[tj], 0.0f);
                        crow[n0 + wn + tj * 16 + ln] = v;
                    }
                }
            }
        }
    }
}

// ---------------------------------------------------------------------------
// Aggregation, wave-per-node, deep-unrolled for memory-level parallelism:
// out[n,:] = bf16(dis[n] * (hs[n,:] + sum_{src in in(n)} hs[src,:]))
// Lanes form G groups of L=F/8; each lane loads uint4 = 8 bf16 (16 B).
// Per outer iteration the wave issues 16 items: UF batches of G items each,
// structured as [all col loads] -> [all row gathers] -> [accumulate] so the
// compiler can keep UF row-loads in flight (2 chained latencies per 16 items).
template<int F>
__global__ __launch_bounds__(256) void agg_kernel(
    const u16* __restrict__ hs, const int* __restrict__ offs,
    const int* __restrict__ col, const float* __restrict__ dis,
    u16* __restrict__ out, int n_nodes)
{
    constexpr int L  = F / 8;                   // lanes per item (16 or 32)
    constexpr int G  = 64 / L;                  // items per batch (4 or 2)
    constexpr int UF = 16 / G;                  // batches per iteration
    const int lane = threadIdx.x & 63;
    const int n    = (blockIdx.x * blockDim.x + threadIdx.x) >> 6;  // wave id
    if (n >= n_nodes) return;
    const int li = lane % L;
    const int gi = lane / L;

    const int lo = offs[n], hi = offs[n + 1];
    const int total = 1 + (hi - lo);            // self + edges

    float acc[8];
#pragma unroll
    for (int i = 0; i < 8; ++i) acc[i] = 0.0f;

    for (int base = 0; base < total; base += G * UF) {
        int  idxs[UF];
        bool valid[UF];
        // phase 1: independent col-index loads
#pragma unroll
        for (int u = 0; u < UF; ++u) {
            int it = base + u * G + gi;
            valid[u] = (it < total);
            idxs[u] = 0;
            if (valid[u]) idxs[u] = (it == 0) ? n : col[lo + it - 1];
        }
        // phase 2: independent row gathers (UF outstanding loads)
        uint4 w[UF];
#pragma unroll
        for (int u = 0; u < UF; ++u)
            if (valid[u])
                w[u] = *(const uint4*)(hs + (size_t)idxs[u] * F + li * 8);
        // phase 3: accumulate
#pragma unroll
        for (int u = 0; u < UF; ++u)
            if (valid[u]) {
                unsigned uu[4] = {w[u].x, w[u].y, w[u].z, w[u].w};
#pragma unroll
                for (int q = 0; q < 4; ++q) {
                    acc[2 * q]     += __uint_as_float(uu[q] << 16);
                    acc[2 * q + 1] += __uint_as_float(uu[q] & 0xFFFF0000u);
                }
            }
    }

    // combine the G partial groups (lane strides L..32)
#pragma unroll
    for (int off = 32; off >= L; off >>= 1)
#pragma unroll
        for (int i = 0; i < 8; ++i)
            acc[i] += __shfl_xor(acc[i], off);

    if (gi == 0) {
        float d = dis[n];
        unsigned r[4];
#pragma unroll
        for (int q = 0; q < 4; ++q) {
            unsigned l16 = (unsigned)f2bf(acc[2 * q] * d);
            unsigned h16 = (unsigned)f2bf(acc[2 * q + 1] * d);
            r[q] = l16 | (h16 << 16);
        }
        *(uint4*)(out + (size_t)n * F + li * 8) = make_uint4(r[0], r[1], r[2], r[3]);
    }
}

// ---------------------------------------------------------------------------
// Pool phase 1: partial column sums per graph, chunked over nodes.
#define POOL_BLOCKS 320
__global__ __launch_bounds__(256) void pool_partial_kernel(
    const float* __restrict__ h, const int* __restrict__ batch,
    float* __restrict__ pooled, int n_nodes)
{
    const int j = threadIdx.x;
    const int per = (n_nodes + POOL_BLOCKS - 1) / POOL_BLOCKS;
    const int start = blockIdx.x * per;
    const int end   = min(start + per, n_nodes);
    if (start >= end) return;

    int curg = batch[start];
    float acc = 0.0f;
    for (int r = start; r < end; ++r) {
        int g = batch[r];
        if (g != curg) {
            atomicAdd(&pooled[(size_t)curg * HID + j], acc);
            acc = 0.0f;
            curg = g;
        }
        acc += h[(size_t)r * HID + j];
    }
    atomicAdd(&pooled[(size_t)curg * HID + j], acc);
}

// Pool phase 2: divide by counts (binary search on sorted batch) + final linear
__global__ __launch_bounds__(256) void pool_finalize_kernel(
    const float* __restrict__ pooled, const int* __restrict__ batch,
    const float* __restrict__ Wlin, const float* __restrict__ blin,
    float* __restrict__ out, int n_nodes)
{
    const int g = blockIdx.x;
    const int j = threadIdx.x;
    int lo = 0, hi = n_nodes;
    while (lo < hi) { int mid = (lo + hi) >> 1; if (batch[mid] < g) lo = mid + 1; else hi = mid; }
    const int start = lo;
    lo = start; hi = n_nodes;
    while (lo < hi) { int mid = (lo + hi) >> 1; if (batch[mid] < g + 1) lo = mid + 1; else hi = mid; }
    const int cnt = lo - start;

    float pv = pooled[(size_t)g * HID + j] / fmaxf((float)cnt, 1.0f);

    __shared__ float pl[HID];
    pl[j] = pv;
    __syncthreads();
    if (j < OUTC) {
        float o = blin[j];
        for (int k = 0; k < HID; ++k) o = fmaf(pl[k], Wlin[k * OUTC + j], o);
        out[g * OUTC + j] = o;
    }
}

// ---------------------------------------------------------------------------
extern "C" void kernel_launch(void* const* d_in, const int* in_sizes, int n_in,
                              void* d_out, int out_size, void* d_ws, size_t ws_size,
                              hipStream_t stream) {
    const float* x     = (const float*)d_in[0];
    const int*   ei    = (const int*)  d_in[1];   // [2, E]: row0 src, row1 dst
    const int*   batch = (const int*)  d_in[2];
    const float* W1    = (const float*)d_in[3];
    const float* b1    = (const float*)d_in[4];
    const float* W2    = (const float*)d_in[5];
    const float* b2    = (const float*)d_in[6];
    const float* Wlin  = (const float*)d_in[7];
    const float* blin  = (const float*)d_in[8];
    float* out = (float*)d_out;

    const int* src = ei;
    const int* dst = ei + EE;

    // workspace layout; h2f aliases [xs|xab|h1s] (exactly 40.96 MB, all dead
    // by the time gemm2 writes h2f)
    char* p = (char*)d_ws;
    char* region0 = p;
    u16*   xs  = (u16*)p;   p += (size_t)NN * INC * sizeof(u16);    // 10.24 MB
    u16*   xab = (u16*)p;   p += (size_t)NN * INC * sizeof(u16);    // 10.24 MB
    u16*   h1s = (u16*)p;   p += (size_t)NN * HID * sizeof(u16);    // 20.48 MB
    u16*   a2b = (u16*)p;   p += (size_t)NN * HID * sizeof(u16);    // 20.48 MB
    u16*   w1h = (u16*)p;   p += (size_t)HID * INC * sizeof(u16);
    u16*   w1l = (u16*)p;   p += (size_t)HID * INC * sizeof(u16);
    u16*   w2h = (u16*)p;   p += (size_t)HID * HID * sizeof(u16);
    u16*   w2l = (u16*)p;   p += (size_t)HID * HID * sizeof(u16);
    float* dis = (float*)p; p += (size_t)NN * sizeof(float);
    float* pooled = (float*)p; p += (size_t)GG * HID * sizeof(float);
    int* cnt    = (int*)p;  p += (size_t)NN * sizeof(int);
    int* offs   = (int*)p;  p += (size_t)(NN + 16) * sizeof(int);
    int* cursor = (int*)p;  p += (size_t)NN * sizeof(int);
    int* col    = (int*)p;  p += (size_t)EE * sizeof(int);
    int* pre    = (int*)p;  p += (size_t)NN * sizeof(int);
    int* bsum   = (int*)p;  p += 512 * sizeof(int);
    int* boff   = (int*)p;  p += 512 * sizeof(int);
    float* h2f  = (float*)region0;   // 40.96 MB alias
    (void)ws_size; (void)n_in; (void)in_sizes; (void)out_size;

    const int TB = 256;
    const int nb_n = (NN + TB - 1) / TB;      // 157
    const int nb_e = (EE + TB - 1) / TB;

    // graph structure (rebuilt every call; ws is re-poisoned)
    init_kernel<<<nb_n, TB, 0, stream>>>(cnt, cursor, NN, pooled, GG * HID);
    count_kernel<<<nb_e, TB, 0, stream>>>(dst, cnt, EE);
    scan1_kernel<<<nb_n, SCAN_B, 0, stream>>>(cnt, pre, bsum, dis, NN);
    scan2_kernel<<<1, SCAN_B, 0, stream>>>(bsum, boff, offs, nb_n, NN);
    scan3_kernel<<<nb_n, SCAN_B, 0, stream>>>(pre, boff, offs, NN);
    fill_kernel<<<nb_e, TB, 0, stream>>>(src, dst, offs, cursor, col, EE);

    // weight transpose + bf16 hi/lo split (both weights, one launch)
    const int wtot = INC * HID + HID * HID;
    wsplit_kernel<<<(wtot + TB - 1) / TB, TB, 0, stream>>>(W1, w1h, w1l, W2, w2h, w2l);

    // xs = bf16(dis .* x)
    const int total4 = NN * INC / 4;
    xs_kernel<<<(total4 + TB - 1) / TB, TB, 0, stream>>>(x, dis, xs, total4);

    dim3 ggrid((NN + BM - 1) / BM, HID / BN);
    const int agg_blocks = (NN * 64 + TB - 1) / TB;   // one wave per node

    // layer 1: xab = bf16(dis .* (xs self + gather)); h1s = bf16(dis .* relu(xab@W1 + b1))
    agg_kernel<INC><<<agg_blocks, TB, 0, stream>>>(xs, offs, col, dis, xab, NN);
    mgemm_kernel<true><<<ggrid, 256, 0, stream>>>(xab, w1h, w1l, b1, dis,
                                                  (void*)h1s, NN, INC);

    // layer 2: a2b = bf16(dis .* (h1s self + gather)); h2f = relu(a2b@W2 + b2)
    agg_kernel<HID><<<agg_blocks, TB, 0, stream>>>(h1s, offs, col, dis, a2b, NN);
    mgemm_kernel<false><<<ggrid, 256, 0, stream>>>(a2b, w2h, w2l, b2, dis,
                                                   (void*)h2f, NN, HID);

    // pool (two-phase) + linear
    pool_partial_kernel<<<POOL_BLOCKS, 256, 0, stream>>>(h2f, batch, pooled, NN);
    pool_finalize_kernel<<<GG, 256, 0, stream>>>(pooled, batch, Wlin, blin, out, NN);
}